// Round 1
// baseline (668.572 us; speedup 1.0000x reference)
//
#include <hip/hip_runtime.h>

// FeatureAggregation: fused deformable-attention-style op.
// Sizes: C=256, H2=256, E=512, SQ=2048, SK=64, HW=256, NH=8, hd=64.
//
// Key index fact (derived from the reference's raw reshape, NOT a transpose):
//   key[q,k,j] for j<256  = bilinear(Z[ch=q>>3], r[q',:]) with
//       q' = 256*(q&7) + 4*k + (j>>6),  point col = j&63
//   key[q,k,256+m]        = r[q,k,0]*w1[m,0] + r[q,k,1]*w1[m,1] + b1[m]
//
// Pipeline: k_prep (f16 weights + query matrix) -> k_gemm64 (ql) ->
//           k_main (per-q fused: key build, kl GEMM, softmax, vl GEMM, attn)
//           -> k_gemm64 (out_proj + q_z copy).

typedef _Float16 half8 __attribute__((ext_vector_type(8)));
typedef float f32x4 __attribute__((ext_vector_type(4)));

#define N_IN_PROJ_H 786432   // 1536*512
#define N_WO_H      262144   // 512*512
#define N_QUERY_H   1048576  // 2048*512

// ---------------- prep: fp32 -> f16 weights, build query matrix ----------------
__global__ __launch_bounds__(256) void k_prep(
    const float* __restrict__ in_proj_w, const float* __restrict__ out_proj_w,
    const float* __restrict__ q_z, const float* __restrict__ Qm,
    const float* __restrict__ w2, const float* __restrict__ b2,
    _Float16* __restrict__ wsh)
{
    int idx = blockIdx.x * 256 + threadIdx.x;
    if (idx < N_IN_PROJ_H) {
        wsh[idx] = (_Float16)in_proj_w[idx];
    } else if (idx < N_IN_PROJ_H + N_WO_H) {
        wsh[idx] = (_Float16)out_proj_w[idx - N_IN_PROJ_H];
    } else {
        int e = idx - (N_IN_PROJ_H + N_WO_H);
        int q = e >> 9, j = e & 511;
        float v;
        if (j < 256) {
            v = q_z[q * 256 + j];
        } else {
            int m = j - 256;
            v = Qm[q * 3 + 0] * w2[m * 3 + 0] + Qm[q * 3 + 1] * w2[m * 3 + 1]
              + Qm[q * 3 + 2] * w2[m * 3 + 2] + b2[m];
        }
        wsh[idx] = (_Float16)v;
    }
}

// ---------------- generic 64-row GEMM: out = A(f16,2048x512) @ B(f16,512x512)^T + bias ----------------
__global__ __launch_bounds__(256) void k_gemm64(
    const _Float16* __restrict__ A, const _Float16* __restrict__ B,
    const float* __restrict__ bias, float* __restrict__ out,
    int out_pitch, int out_col0, const float* __restrict__ qz, int copy_qz)
{
    __shared__ __align__(16) _Float16 sA[64][520];
    int q0 = blockIdx.x * 64;
    int t = threadIdx.x, w = t >> 6, l = t & 63;

    const _Float16* Ab = A + (size_t)q0 * 512;
#pragma unroll
    for (int i = 0; i < 16; ++i) {
        int e = i * 2048 + t * 8;
        int row = e >> 9, col = e & 511;
        *(half8*)&sA[row][col] = *(const half8*)(Ab + e);
    }
    if (copy_qz) {
#pragma unroll
        for (int i = 0; i < 16; ++i) {
            int idx4 = i * 256 + t;
            int row = idx4 >> 6, c = (idx4 & 63) << 2;
            *(float4*)&out[(size_t)(q0 + row) * out_pitch + c] =
                *(const float4*)&qz[(size_t)(q0 + row) * 256 + c];
        }
    }
    __syncthreads();

    f32x4 acc[4][8] = {};
    int arow = l & 15, kg = (l >> 4) << 3;
    const _Float16* Bb = B + (size_t)((w << 7) + arow) * 512 + kg;
    for (int kk = 0; kk < 512; kk += 32) {
        half8 a[4], bb[8];
#pragma unroll
        for (int mt = 0; mt < 4; ++mt) a[mt] = *(const half8*)&sA[mt * 16 + arow][kk + kg];
#pragma unroll
        for (int nt = 0; nt < 8; ++nt) bb[nt] = *(const half8*)(Bb + kk + nt * 16 * 512);
#pragma unroll
        for (int mt = 0; mt < 4; ++mt)
#pragma unroll
            for (int nt = 0; nt < 8; ++nt)
                acc[mt][nt] = __builtin_amdgcn_mfma_f32_16x16x32_f16(a[mt], bb[nt], acc[mt][nt], 0, 0, 0);
    }
#pragma unroll
    for (int mt = 0; mt < 4; ++mt)
#pragma unroll
        for (int nt = 0; nt < 8; ++nt)
#pragma unroll
            for (int v = 0; v < 4; ++v) {
                int row = mt * 16 + ((l >> 4) << 2) + v;
                int col = (w << 7) + nt * 16 + arow;
                out[(size_t)(q0 + row) * out_pitch + out_col0 + col] = acc[mt][nt][v] + bias[col];
            }
}

// ---------------- per-q fused GEMM helper: sOut = sA(64x512) @ B^T + bias, f16 out ----------------
__device__ __forceinline__ void gemm_tile64(_Float16 (*sA)[520], const _Float16* __restrict__ B,
                                            const float* __restrict__ bias, _Float16 (*sOut)[520],
                                            int w, int l)
{
    f32x4 acc[4][4] = {};
    int arow = l & 15, kg = (l >> 4) << 3;
    const _Float16* Bb = B + (size_t)((w << 6) + arow) * 512 + kg;
#pragma unroll 2
    for (int kk = 0; kk < 512; kk += 32) {
        half8 a[4], bb[4];
#pragma unroll
        for (int mt = 0; mt < 4; ++mt) a[mt] = *(const half8*)&sA[mt * 16 + arow][kk + kg];
#pragma unroll
        for (int nt = 0; nt < 4; ++nt) bb[nt] = *(const half8*)(Bb + kk + nt * 16 * 512);
#pragma unroll
        for (int mt = 0; mt < 4; ++mt)
#pragma unroll
            for (int nt = 0; nt < 4; ++nt)
                acc[mt][nt] = __builtin_amdgcn_mfma_f32_16x16x32_f16(a[mt], bb[nt], acc[mt][nt], 0, 0, 0);
    }
#pragma unroll
    for (int mt = 0; mt < 4; ++mt)
#pragma unroll
        for (int nt = 0; nt < 4; ++nt)
#pragma unroll
            for (int v = 0; v < 4; ++v) {
                int row = mt * 16 + ((l >> 4) << 2) + v;
                int col = (w << 6) + nt * 16 + arow;
                sOut[row][col] = (_Float16)(acc[mt][nt][v] + bias[col]);
            }
}

// ---------------- main fused kernel: one block per query q ----------------
__global__ __launch_bounds__(512, 2) void k_main(
    const float* __restrict__ Z, const float* __restrict__ r,
    const float* __restrict__ w1, const float* __restrict__ b1,
    const float* __restrict__ in_proj_b,
    const _Float16* __restrict__ wk, const _Float16* __restrict__ wv,
    const float* __restrict__ ql_g, _Float16* __restrict__ ao)
{
    __shared__ __align__(16) _Float16 sKey[64][520];
    __shared__ __align__(16) _Float16 sKV[64][520];
    __shared__ __align__(16) float sQl[512];
    __shared__ __align__(16) float sP[512];

    int b = blockIdx.x;
    // XCD swizzle: the 8 q's sharing channel q>>3 land on the same XCD (b%8).
    int q = 8 * ((b & 7) + ((b >> 6) << 3)) + ((b >> 3) & 7);
    int t = threadIdx.x, w = t >> 6, l = t & 63;

    sQl[t] = ql_g[(size_t)q * 512 + t];

    // ---- phase 1: build key tile (bilinear gather + r_proj) ----
    int ch = q >> 3, s8 = q & 7;
    const float* Zc = Z + ((size_t)ch << 16);
    const float2* r2 = (const float2*)r;
    int m = t & 255;
    float w10 = w1[2 * m], w11 = w1[2 * m + 1], b1m = b1[m];
    const float* rq = r + (size_t)q * 128;
    int jcol = ((w & 3) << 6) + l;
    int wq4 = w >> 2;
#pragma unroll 4
    for (int i = 0; i < 32; ++i) {
        int k = 2 * i + wq4;
        int qp = (s8 << 8) + 4 * k + (jcol >> 6);
        float2 rv = r2[(qp << 6) + l];
        int x1 = (int)rv.x, y1 = (int)rv.y;
        float dx = rv.x - (float)x1, dy = rv.y - (float)y1;
        const float* zb = Zc + (x1 << 8) + y1;
        float q11 = zb[0], q12 = zb[1], q21 = zb[256], q22 = zb[257];
        float R1 = q11 + dx * (q21 - q11);
        float R2 = q12 + dx * (q22 - q12);
        float vz = R1 + dy * (R2 - R1);
        sKey[k][jcol] = (_Float16)vz;
        float rr0 = rq[2 * k], rr1 = rq[2 * k + 1];
        sKey[k][256 + m] = (_Float16)(rr0 * w10 + rr1 * w11 + b1m);
    }
    __syncthreads();

    // ---- phase 2: kl = key @ Wk^T + bk ----
    gemm_tile64(sKey, wk, in_proj_b + 512, sKV, w, l);
    __syncthreads();

    // ---- phase 3: scores[h,k] = 0.125 * <ql[h*64:], kl[k, h*64:]> ----
    {
        int h = t >> 6, k = t & 63;
        const half8* kr = (const half8*)&sKV[k][h << 6];
        const float4* qr4 = (const float4*)&sQl[h << 6];
        float s = 0.f;
#pragma unroll
        for (int d8 = 0; d8 < 8; ++d8) {
            half8 kv = kr[d8];
            float4 qa = qr4[2 * d8], qb = qr4[2 * d8 + 1];
            s += qa.x * (float)kv[0] + qa.y * (float)kv[1] + qa.z * (float)kv[2] + qa.w * (float)kv[3]
               + qb.x * (float)kv[4] + qb.y * (float)kv[5] + qb.z * (float)kv[6] + qb.w * (float)kv[7];
        }
        sP[t] = s * 0.125f;
    }
    __syncthreads();

    // ---- phase 4: softmax per head (wave w == head w) + vl GEMM ----
    {
        float v = sP[t];
        float mx = v;
#pragma unroll
        for (int mm = 1; mm < 64; mm <<= 1) mx = fmaxf(mx, __shfl_xor(mx, mm, 64));
        float e = expf(v - mx);
        float sm = e;
#pragma unroll
        for (int mm = 1; mm < 64; mm <<= 1) sm += __shfl_xor(sm, mm, 64);
        sP[t] = e / sm;
    }
    gemm_tile64(sKey, wv, in_proj_b + 1024, sKV, w, l);
    __syncthreads();

    // ---- phase 5: ao[n] = sum_k attn[h,k] * vl[k,n],  h = n>>6 ----
    {
        int h = t >> 6;
        float acc2 = 0.f;
#pragma unroll
        for (int k = 0; k < 64; ++k) acc2 += sP[(h << 6) + k] * (float)sKV[k][t];
        ao[(size_t)q * 512 + t] = (_Float16)acc2;
    }
}

extern "C" void kernel_launch(void* const* d_in, const int* in_sizes, int n_in,
                              void* d_out, int out_size, void* d_ws, size_t ws_size,
                              hipStream_t stream) {
    const float* Z          = (const float*)d_in[0];
    const float* Qm         = (const float*)d_in[1];
    const float* q_z        = (const float*)d_in[2];
    const float* r          = (const float*)d_in[3];
    const float* w1         = (const float*)d_in[4];
    const float* b1         = (const float*)d_in[5];
    const float* w2         = (const float*)d_in[6];
    const float* b2         = (const float*)d_in[7];
    const float* in_proj_w  = (const float*)d_in[8];
    const float* in_proj_b  = (const float*)d_in[9];
    const float* out_proj_w = (const float*)d_in[10];
    const float* out_proj_b = (const float*)d_in[11];
    float* out = (float*)d_out;

    _Float16* wsh   = (_Float16*)d_ws;
    _Float16* wq    = wsh;                       // in_proj rows [0,512)
    _Float16* wk    = wsh + 262144;              // rows [512,1024)
    _Float16* wv    = wsh + 524288;              // rows [1024,1536)
    _Float16* wo    = wsh + 786432;              // out_proj
    _Float16* query = wsh + 1048576;             // 2048x512 f16
    float*    ql    = (float*)((char*)d_ws + 4194304);    // 2048x512 f32
    _Float16* ao    = (_Float16*)((char*)d_ws + 8388608); // 2048x512 f16

    k_prep<<<8192, 256, 0, stream>>>(in_proj_w, out_proj_w, q_z, Qm, w2, b2, wsh);
    k_gemm64<<<32, 256, 0, stream>>>(query, wq, in_proj_b, ql, 512, 0, nullptr, 0);
    k_main<<<2048, 512, 0, stream>>>(Z, r, w1, b1, in_proj_b, wk, wv, ql, ao);
    k_gemm64<<<32, 256, 0, stream>>>(ao, wo, out_proj_b, out, 768, 256, q_z, 1);
}

// Round 2
// 496.598 us; speedup vs baseline: 1.3463x; 1.3463x over previous
//
#include <hip/hip_runtime.h>

// FeatureAggregation, round 2: algebraic elimination of the kl/vl GEMMs.
//   scores[q,h,k] = key[q,k,:] . u[q,h,:],  u = (ql_h @ Wk_h) * 0.125   (bk drops out of softmax)
//   out = G @ M + b_eff,  g[q,h,:] = attn[q,h,:] @ key[q],
//   M[h*512+j, e] = sum_d Wv[h*64+d, j] * Wo[e, h*64+d],  b_eff = Wo@bv + bo
// Sizes: C=256, HW=256, E=512, SQ=2048, SK=64, NH=8, hd=64.
//
// key index fact (reference's raw reshape):
//   key[q,k,j<256] = bilinear(Z[q>>3], r[256*(q&7) + 4k + (j>>6), j&63])
//   key[q,k,256+m] = r[q,k,:] . w1[m,:] + b1[m]

typedef _Float16 half8 __attribute__((ext_vector_type(8)));
typedef _Float16 half2v __attribute__((ext_vector_type(2)));
typedef float f32x4 __attribute__((ext_vector_type(4)));

__device__ __forceinline__ float dot8f(half8 a, half8 b, float s) {
    half2v a0 = __builtin_shufflevector(a, a, 0, 1), b0 = __builtin_shufflevector(b, b, 0, 1);
    half2v a1 = __builtin_shufflevector(a, a, 2, 3), b1 = __builtin_shufflevector(b, b, 2, 3);
    half2v a2 = __builtin_shufflevector(a, a, 4, 5), b2 = __builtin_shufflevector(b, b, 4, 5);
    half2v a3 = __builtin_shufflevector(a, a, 6, 7), b3 = __builtin_shufflevector(b, b, 6, 7);
    s = __builtin_amdgcn_fdot2(a0, b0, s, false);
    s = __builtin_amdgcn_fdot2(a1, b1, s, false);
    s = __builtin_amdgcn_fdot2(a2, b2, s, false);
    s = __builtin_amdgcn_fdot2(a3, b3, s, false);
    return s;
}

// ---- prep: f16 weights (+transposed per-head slices), query matrix, b_eff ----
#define P_WQ    0
#define P_WO    262144
#define P_WKT   524288
#define P_WVT   786432
#define P_QRY   1048576
#define P_BEFF  2097152
#define P_END   2097664

__global__ __launch_bounds__(256) void k_prep(
    const float* __restrict__ ipw, const float* __restrict__ opw,
    const float* __restrict__ q_z, const float* __restrict__ Qm,
    const float* __restrict__ w2, const float* __restrict__ b2,
    const float* __restrict__ ipb, const float* __restrict__ opb,
    _Float16* __restrict__ wsh, float* __restrict__ b_eff)
{
    int idx = blockIdx.x * 256 + threadIdx.x;
    if (idx < P_WO) {
        wsh[idx] = (_Float16)ipw[idx];
    } else if (idx < P_WKT) {
        wsh[idx] = (_Float16)opw[idx - P_WO];
    } else if (idx < P_WVT) {
        int e = idx - P_WKT;
        int h = e >> 15, j = (e >> 6) & 511, d = e & 63;
        wsh[idx] = (_Float16)(0.125f * ipw[(size_t)(512 + (h << 6) + d) * 512 + j]);
    } else if (idx < P_QRY) {
        int e = idx - P_WVT;
        int h = e >> 15, j = (e >> 6) & 511, d = e & 63;
        wsh[idx] = (_Float16)ipw[(size_t)(1024 + (h << 6) + d) * 512 + j];
    } else if (idx < P_BEFF) {
        int e = idx - P_QRY;
        int q = e >> 9, j = e & 511;
        float v;
        if (j < 256) v = q_z[q * 256 + j];
        else {
            int m = j - 256;
            v = Qm[q * 3] * w2[m * 3] + Qm[q * 3 + 1] * w2[m * 3 + 1]
              + Qm[q * 3 + 2] * w2[m * 3 + 2] + b2[m];
        }
        wsh[idx] = (_Float16)v;
    } else if (idx < P_END) {
        int e = idx - P_BEFF;
        float s = opb[e];
        const float* worow = opw + (size_t)e * 512;
        for (int n = 0; n < 512; ++n) s += ipb[1024 + n] * worow[n];
        b_eff[e] = s;
    }
}

// ---- ql = query @ Wq^T + bq  (f16 out, 2048x512), 32 blocks x 256 ----
__global__ __launch_bounds__(256) void k_ql(
    const _Float16* __restrict__ A, const _Float16* __restrict__ B,
    const float* __restrict__ bias, _Float16* __restrict__ out)
{
    __shared__ __align__(16) _Float16 sA[64][520];
    int q0 = blockIdx.x * 64;
    int t = threadIdx.x, w = t >> 6, l = t & 63;
    const _Float16* Ab = A + (size_t)q0 * 512;
#pragma unroll
    for (int i = 0; i < 16; ++i) {
        int e = i * 2048 + t * 8;
        *(half8*)&sA[e >> 9][e & 511] = *(const half8*)(Ab + e);
    }
    __syncthreads();
    f32x4 acc[4][8] = {};
    int arow = l & 15, kg = (l >> 4) << 3;
    const _Float16* Bb = B + (size_t)((w << 7) + arow) * 512 + kg;
    for (int kk = 0; kk < 512; kk += 32) {
        half8 a[4], bb[8];
#pragma unroll
        for (int mt = 0; mt < 4; ++mt) a[mt] = *(const half8*)&sA[mt * 16 + arow][kk + kg];
#pragma unroll
        for (int nt = 0; nt < 8; ++nt) bb[nt] = *(const half8*)(Bb + kk + nt * 16 * 512);
#pragma unroll
        for (int mt = 0; mt < 4; ++mt)
#pragma unroll
            for (int nt = 0; nt < 8; ++nt)
                acc[mt][nt] = __builtin_amdgcn_mfma_f32_16x16x32_f16(a[mt], bb[nt], acc[mt][nt], 0, 0, 0);
    }
#pragma unroll
    for (int mt = 0; mt < 4; ++mt)
#pragma unroll
        for (int nt = 0; nt < 8; ++nt)
#pragma unroll
            for (int v = 0; v < 4; ++v) {
                int row = mt * 16 + ((l >> 4) << 2) + v;
                int col = (w << 7) + nt * 16 + arow;
                out[(size_t)(q0 + row) * 512 + col] = (_Float16)(acc[mt][nt][v] + bias[col]);
            }
}

// ---- small GEMM: C[rb*64.., h*512..] = A[rb*64.., h*64..](64xK64) @ BT_h(512x64)^T ----
// used for U (A=qlh) and Mt (A=wo). Output pitch 4096, f16.
__global__ __launch_bounds__(256) void k_small(
    const _Float16* __restrict__ A, const _Float16* __restrict__ BT,
    _Float16* __restrict__ C)
{
    __shared__ __align__(16) _Float16 sA[64][72];
    int rb = blockIdx.x, h = blockIdx.y;
    int t = threadIdx.x, w = t >> 6, l = t & 63;
    const _Float16* A0 = A + (size_t)rb * 64 * 512 + h * 64;
    const _Float16* B0 = BT + (size_t)h * 512 * 64;
    _Float16* C0 = C + (size_t)rb * 64 * 4096 + h * 512;
#pragma unroll
    for (int i = 0; i < 2; ++i) {
        int g = t + i * 256;
        int row = g >> 3, colg = (g & 7) * 8;
        *(half8*)&sA[row][colg] = *(const half8*)(A0 + (size_t)row * 512 + colg);
    }
    __syncthreads();
    f32x4 acc[4][8] = {};
    int arow = l & 15, kg = (l >> 4) << 3;
#pragma unroll
    for (int kk = 0; kk < 64; kk += 32) {
        half8 a[4], bb[8];
#pragma unroll
        for (int mt = 0; mt < 4; ++mt) a[mt] = *(const half8*)&sA[mt * 16 + arow][kk + kg];
#pragma unroll
        for (int nt = 0; nt < 8; ++nt) {
            int col = (w << 7) + nt * 16 + arow;
            bb[nt] = *(const half8*)(B0 + (size_t)col * 64 + kk + kg);
        }
#pragma unroll
        for (int mt = 0; mt < 4; ++mt)
#pragma unroll
            for (int nt = 0; nt < 8; ++nt)
                acc[mt][nt] = __builtin_amdgcn_mfma_f32_16x16x32_f16(a[mt], bb[nt], acc[mt][nt], 0, 0, 0);
    }
#pragma unroll
    for (int mt = 0; mt < 4; ++mt)
#pragma unroll
        for (int nt = 0; nt < 8; ++nt)
#pragma unroll
            for (int v = 0; v < 4; ++v) {
                int row = mt * 16 + ((l >> 4) << 2) + v;
                int col = (w << 7) + nt * 16 + arow;
                C0[(size_t)row * 4096 + col] = (_Float16)acc[mt][nt][v];
            }
}

// ---- main fused kernel: one block per q. gather -> scores -> softmax -> g ----
__global__ __launch_bounds__(512, 2) void k_main(
    const float* __restrict__ Z, const float* __restrict__ r,
    const float* __restrict__ w1, const float* __restrict__ b1,
    const _Float16* __restrict__ U, _Float16* __restrict__ G)
{
    __shared__ __align__(16) _Float16 sKey[64][520];
    __shared__ __align__(16) _Float16 sU[8][520];
    __shared__ __align__(16) float sP[512];

    int b = blockIdx.x;
    // XCD swizzle: 8 q's sharing channel q>>3 land on the same XCD (b%8).
    int q = 8 * ((b & 7) + ((b >> 6) << 3)) + ((b >> 3) & 7);
    int t = threadIdx.x, w = t >> 6, l = t & 63;

    // load u[q] (8KB): t -> (h=t>>6, jg8=t&63); U[q, h*512+jg8*8] == U[q, t*8]
    *(half8*)&sU[w][(t & 63) * 8] = *(const half8*)(U + (size_t)q * 4096 + t * 8);

    // ---- gather + r_proj -> sKey ----
    int ch = q >> 3, s8 = q & 7;
    const float* Zc = Z + ((size_t)ch << 16);
    const float2* r2 = (const float2*)r;
    int m = t & 255;
    float w10 = w1[2 * m], w11 = w1[2 * m + 1], b1m = b1[m];
    const float* rq = r + (size_t)q * 128;
    int jcol = ((w & 3) << 6) + l;
    int wq4 = w >> 2;
#pragma unroll 4
    for (int i = 0; i < 32; ++i) {
        int k = 2 * i + wq4;
        int qp = (s8 << 8) + 4 * k + (jcol >> 6);
        float2 rv = r2[(qp << 6) + l];
        int x1 = (int)rv.x, y1 = (int)rv.y;
        float dx = rv.x - (float)x1, dy = rv.y - (float)y1;
        const float* zb = Zc + (x1 << 8) + y1;
        float q11 = zb[0], q12 = zb[1], q21 = zb[256], q22 = zb[257];
        float R1 = q11 + dx * (q21 - q11);
        float R2 = q12 + dx * (q22 - q12);
        sKey[k][jcol] = (_Float16)(R1 + dy * (R2 - R1));
        float rr0 = rq[2 * k], rr1 = rq[2 * k + 1];
        sKey[k][256 + m] = (_Float16)(rr0 * w10 + rr1 * w11 + b1m);
    }
    __syncthreads();

    // ---- scores: thread -> (k = w*8 + l>>3, h = l&7); conflict-free broadcast reads ----
    {
        int k = (w << 3) + (l >> 3), h = l & 7;
        const half8* kr = (const half8*)&sKey[k][0];
        const half8* ur = (const half8*)&sU[h][0];
        float s = 0.f;
#pragma unroll 8
        for (int jg = 0; jg < 64; ++jg) s = dot8f(kr[jg], ur[jg], s);
        sP[(h << 6) + k] = s;
    }
    __syncthreads();

    // ---- softmax per head (wave w == head) ----
    {
        float v = sP[t];
        float mx = v;
#pragma unroll
        for (int mm = 1; mm < 64; mm <<= 1) mx = fmaxf(mx, __shfl_xor(mx, mm, 64));
        float e = __expf(v - mx);
        float sm = e;
#pragma unroll
        for (int mm = 1; mm < 64; mm <<= 1) sm += __shfl_xor(sm, mm, 64);
        sP[t] = e / sm;
    }
    __syncthreads();

    // ---- g[w, l*8..l*8+8] = sum_k attn[w,k] * key[k, l*8..] ; write G[q, w*512 + l*8] ----
    {
        const float* attn = &sP[w << 6];
        float g8[8] = {};
#pragma unroll 8
        for (int k = 0; k < 64; ++k) {
            half8 kv = *(const half8*)&sKey[k][l * 8];
            float a = attn[k];
#pragma unroll
            for (int x = 0; x < 8; ++x) g8[x] += a * (float)kv[x];
        }
        half8 go;
#pragma unroll
        for (int x = 0; x < 8; ++x) go[x] = (_Float16)g8[x];
        *(half8*)(G + (size_t)q * 4096 + (w << 9) + l * 8) = go;
    }
}

// ---- final: out[:,256:768] = G(2048x4096) @ Mt^T + b_eff ; out[:,0:256] = q_z ----
__global__ __launch_bounds__(256) void k_final(
    const _Float16* __restrict__ G, const _Float16* __restrict__ Mt,
    const float* __restrict__ b_eff, const float* __restrict__ qz,
    float* __restrict__ out)
{
    __shared__ __align__(16) _Float16 sA[64][520];
    int rb = blockIdx.x, cb = blockIdx.y;
    int q0 = rb * 64;
    int t = threadIdx.x, w = t >> 6, l = t & 63;

    if (cb == 0) {
#pragma unroll
        for (int i = 0; i < 16; ++i) {
            int idx4 = i * 256 + t;
            int row = idx4 >> 6, c = (idx4 & 63) << 2;
            *(float4*)&out[(size_t)(q0 + row) * 768 + c] =
                *(const float4*)&qz[(size_t)(q0 + row) * 256 + c];
        }
    }

    f32x4 acc[4][4] = {};
    int arow = l & 15, kg = (l >> 4) << 3;
    for (int c = 0; c < 8; ++c) {
#pragma unroll
        for (int i = 0; i < 16; ++i) {
            int g = t + i * 256;
            int row = g >> 6, colg = (g & 63) * 8;
            *(half8*)&sA[row][colg] = *(const half8*)(G + (size_t)(q0 + row) * 4096 + c * 512 + colg);
        }
        __syncthreads();
#pragma unroll 2
        for (int kk = 0; kk < 512; kk += 32) {
            half8 a[4], bb[4];
#pragma unroll
            for (int mt = 0; mt < 4; ++mt) a[mt] = *(const half8*)&sA[mt * 16 + arow][kk + kg];
#pragma unroll
            for (int nt = 0; nt < 4; ++nt) {
                int ecol = cb * 256 + (w << 6) + nt * 16 + arow;
                bb[nt] = *(const half8*)(Mt + (size_t)ecol * 4096 + c * 512 + kk + kg);
            }
#pragma unroll
            for (int mt = 0; mt < 4; ++mt)
#pragma unroll
                for (int nt = 0; nt < 4; ++nt)
                    acc[mt][nt] = __builtin_amdgcn_mfma_f32_16x16x32_f16(a[mt], bb[nt], acc[mt][nt], 0, 0, 0);
        }
        __syncthreads();
    }
#pragma unroll
    for (int mt = 0; mt < 4; ++mt)
#pragma unroll
        for (int nt = 0; nt < 4; ++nt)
#pragma unroll
            for (int v = 0; v < 4; ++v) {
                int row = mt * 16 + ((l >> 4) << 2) + v;
                int ecol = cb * 256 + (w << 6) + nt * 16 + arow;
                out[(size_t)(q0 + row) * 768 + 256 + ecol] = acc[mt][nt][v] + b_eff[ecol];
            }
}

extern "C" void kernel_launch(void* const* d_in, const int* in_sizes, int n_in,
                              void* d_out, int out_size, void* d_ws, size_t ws_size,
                              hipStream_t stream) {
    const float* Z          = (const float*)d_in[0];
    const float* Qm         = (const float*)d_in[1];
    const float* q_z        = (const float*)d_in[2];
    const float* r          = (const float*)d_in[3];
    const float* w1         = (const float*)d_in[4];
    const float* b1         = (const float*)d_in[5];
    const float* w2         = (const float*)d_in[6];
    const float* b2         = (const float*)d_in[7];
    const float* in_proj_w  = (const float*)d_in[8];
    const float* in_proj_b  = (const float*)d_in[9];
    const float* out_proj_w = (const float*)d_in[10];
    const float* out_proj_b = (const float*)d_in[11];
    float* out = (float*)d_out;

    _Float16* wsh = (_Float16*)d_ws;
    _Float16* wq    = wsh + P_WQ;
    _Float16* wo    = wsh + P_WO;
    _Float16* wkT   = wsh + P_WKT;
    _Float16* wvT   = wsh + P_WVT;
    _Float16* query = wsh + P_QRY;
    _Float16* qlh   = wsh + 2097152;              // 2048x512
    _Float16* U     = wsh + 3145728;              // 2048x4096
    _Float16* G     = wsh + 11534336;             // 2048x4096
    _Float16* Mt    = wsh + 19922944;             // 512x4096
    float*    b_eff = (float*)((char*)d_ws + 44040192);  // 512 f32

    k_prep<<<8194, 256, 0, stream>>>(in_proj_w, out_proj_w, q_z, Qm, w2, b2,
                                     in_proj_b, out_proj_b, wsh, b_eff);
    k_ql<<<32, 256, 0, stream>>>(query, wq, in_proj_b, qlh);
    k_small<<<dim3(32, 8), 256, 0, stream>>>(qlh, wkT, U);
    k_small<<<dim3(8, 8), 256, 0, stream>>>(wo, wvT, Mt);
    k_main<<<2048, 512, 0, stream>>>(Z, r, w1, b1, U, G);
    k_final<<<dim3(32, 2), 256, 0, stream>>>(G, Mt, b_eff, q_z, out);
}

// Round 3
// 321.353 us; speedup vs baseline: 2.0805x; 1.5453x over previous
//
#include <hip/hip_runtime.h>

// FeatureAggregation, round 3: channel-contiguous gather + MFMA scores.
// Pipeline:
//   k_prep  : f16 weights (wqT, wkT*0.125 [h][j][d], wvT [h][j][d], wo), query, bu, b_eff
//   k_zt    : Z [c][x][y] f32 -> Zt [x][y][c] f16   (coalesced LDS transpose)
//   k_small : WcT[c][i] = (wqT @ wkT)^T  and  Mt[e][c] = wo @ wvT
//   k_gemmU : U = query @ WcT^T + bu   (2048x4096 f16)
//   k_passA : bilinear interp, channel-contiguous reads -> Zr[ch][qp][col] f16
//   k_main  : per-q: load key tile (contiguous) -> MFMA scores -> softmax -> g -> G
//   k_final : out[:,256:768] = G @ Mt^T + b_eff (64x64 tiles), out[:,0:256] = q_z
//
// key index fact (reference's raw reshape):
//   key[q,k,j<256] = bilinear(Z[q>>3], r[256*(q&7) + 4k + (j>>6), j&63])
//   key[q,k,256+m] = r[q,k,:] . w1[m,:] + b1[m]

typedef _Float16 half8 __attribute__((ext_vector_type(8)));
typedef _Float16 half4v __attribute__((ext_vector_type(4)));
typedef float f32x4 __attribute__((ext_vector_type(4)));

// ---------------- ws element offsets (f16 units) ----------------
#define O_WQT   0u          // 512*512
#define O_WKT   262144u     // [8][512][64] * 0.125
#define O_WVT   524288u     // [8][512][64]
#define O_WO    786432u     // 512*512
#define O_QRY   1048576u    // 2048*512
#define O_WCT   2097152u    // [4096][512]
#define O_MT    4194304u    // [512][4096]
#define O_U     6291456u    // 2048*4096
#define O_G     14680064u   // 2048*4096
#define O_ZT    23068672u   // 256*256*256
#define O_ZR    39845888u   // 256*2048*64
#define O_F32   73400320u   // f32 region starts here (bu 4096, b_eff 512)

// ---------------- prep ----------------
__global__ __launch_bounds__(256) void k_prep(
    const float* __restrict__ ipw, const float* __restrict__ opw,
    const float* __restrict__ q_z, const float* __restrict__ Qm,
    const float* __restrict__ w2, const float* __restrict__ b2,
    const float* __restrict__ ipb, const float* __restrict__ opb,
    _Float16* __restrict__ wsh, float* __restrict__ bu, float* __restrict__ b_eff)
{
    int idx = blockIdx.x * 256 + threadIdx.x;
    if (idx < 1048576) {                       // query
        int q = idx >> 9, j = idx & 511;
        float v;
        if (j < 256) v = q_z[q * 256 + j];
        else {
            int m = j - 256;
            v = Qm[q * 3] * w2[m * 3] + Qm[q * 3 + 1] * w2[m * 3 + 1]
              + Qm[q * 3 + 2] * w2[m * 3 + 2] + b2[m];
        }
        wsh[O_QRY + idx] = (_Float16)v;
    } else if (idx < 1310720) {                // wqT[i][e] = Wq[e][i]
        int e0 = idx - 1048576;
        int i = e0 >> 9, e = e0 & 511;
        wsh[O_WQT + e0] = (_Float16)ipw[(size_t)e * 512 + i];
    } else if (idx < 1572864) {                // wkT[h][j][d] = 0.125*Wk[h*64+d][j]
        int e0 = idx - 1310720;
        int d = e0 & 63, j = (e0 >> 6) & 511, h = e0 >> 15;
        wsh[O_WKT + e0] = (_Float16)(0.125f * ipw[(size_t)(512 + (h << 6) + d) * 512 + j]);
    } else if (idx < 1835008) {                // wvT[h][j][d] = Wv[h*64+d][j]
        int e0 = idx - 1572864;
        int d = e0 & 63, j = (e0 >> 6) & 511, h = e0 >> 15;
        wsh[O_WVT + e0] = (_Float16)ipw[(size_t)(1024 + (h << 6) + d) * 512 + j];
    } else if (idx < 2097152) {                // wo
        int e0 = idx - 1835008;
        wsh[O_WO + e0] = (_Float16)opw[e0];
    } else if (idx < 2101248) {                // bu[c] = 0.125 * sum_d bq[h*64+d]*Wk[h*64+d][j]
        int c = idx - 2097152;
        int h = c >> 9, j = c & 511;
        float s = 0.f;
        for (int d = 0; d < 64; ++d)
            s += ipb[512 + (h << 6) + d] * ipw[(size_t)(512 + (h << 6) + d) * 512 + j];
        bu[c] = 0.125f * s;
    } else if (idx < 2101760) {                // b_eff[e] = opb[e] + sum_n ipb[1024+n]*Wo[e][n]
        int e = idx - 2101248;
        float s = opb[e];
        const float* worow = opw + (size_t)e * 512;
        for (int n = 0; n < 512; ++n) s += ipb[1024 + n] * worow[n];
        b_eff[e] = s;
    }
}

// ---------------- Z transpose: [c][x][y] f32 -> Zt[x][y][c] f16 ----------------
__global__ __launch_bounds__(256) void k_zt(
    const float* __restrict__ Z, _Float16* __restrict__ Zt)
{
    __shared__ float sT[256][67];
    int x = blockIdx.x, yt = blockIdx.y * 64;
    int t = threadIdx.x;
#pragma unroll
    for (int i = 0; i < 16; ++i) {
        int c = i * 16 + (t >> 4), y = (t & 15) * 4;
        float4 v = *(const float4*)(Z + (size_t)c * 65536 + x * 256 + yt + y);
        sT[c][y] = v.x; sT[c][y + 1] = v.y; sT[c][y + 2] = v.z; sT[c][y + 3] = v.w;
    }
    __syncthreads();
    // thread t == channel; lanes sweep consecutive c on store
    _Float16* outb = Zt + ((size_t)(x * 256 + yt)) * 256 + t;
#pragma unroll 8
    for (int y = 0; y < 64; ++y)
        outb[(size_t)y * 256] = (_Float16)sT[t][y];
}

// ---------------- pass A: interp -> Zr[ch][qp][col] ----------------
__global__ __launch_bounds__(256, 4) void k_passA(
    const _Float16* __restrict__ Zt, const float* __restrict__ r,
    _Float16* __restrict__ Zr)
{
    __shared__ float sT[256][33];
    int b = blockIdx.x;                 // b*32 .. b*32+31 = global points
    int t = threadIdx.x, w = t >> 6, l = t & 63;
    const float2* r2 = (const float2*)r;

#pragma unroll 2
    for (int i = 0; i < 8; ++i) {
        int ptl = w * 8 + i;            // 0..31
        float2 rv = r2[b * 32 + ptl];
        int x1 = (int)rv.x, y1 = (int)rv.y;
        float dx = rv.x - (float)x1, dy = rv.y - (float)y1;
        float w11 = (1.f - dx) * (1.f - dy), w21 = dx * (1.f - dy);
        float w12 = (1.f - dx) * dy,         w22 = dx * dy;
        const _Float16* base = Zt + ((size_t)(x1 * 256 + y1)) * 256;
#pragma unroll
        for (int cg = 0; cg < 4; ++cg) {
            int c = (cg << 6) + l;
            float z11 = (float)base[c];
            float z12 = (float)base[256 + c];
            float z21 = (float)base[65536 + c];
            float z22 = (float)base[65536 + 256 + c];
            sT[c][ptl] = w11 * z11 + w21 * z21 + w12 * z12 + w22 * z22;
        }
    }
    __syncthreads();
    // out: thread -> (ch = g*64 + t>>2, colc = (t&3)*8); lanes give 16 ch x 32 cols per instr
    int ch0 = t >> 2, colc = (t & 3) * 8;
#pragma unroll
    for (int g = 0; g < 4; ++g) {
        int ch = g * 64 + ch0;
        half8 o;
#pragma unroll
        for (int j = 0; j < 8; ++j) o[j] = (_Float16)sT[ch][colc + j];
        *(half8*)(Zr + (size_t)ch * 131072 + b * 32 + colc) = o;
    }
}

// ---- small GEMM: C = A[rb*64.., h*64..](64x64K) @ BT_h(512x64)^T ----
// outT=0: C[rb*64+row][4096-pitch, col h*512+j]   (Mt)
// outT=1: C[(h*512+col)*512 + rb*64+row]          (WcT)
__global__ __launch_bounds__(256) void k_small(
    const _Float16* __restrict__ A, const _Float16* __restrict__ BT,
    _Float16* __restrict__ C, int outT)
{
    __shared__ __align__(16) _Float16 sA[64][72];
    int rb = blockIdx.x, h = blockIdx.y;
    int t = threadIdx.x, w = t >> 6, l = t & 63;
    const _Float16* A0 = A + (size_t)rb * 64 * 512 + h * 64;
    const _Float16* B0 = BT + (size_t)h * 512 * 64;
#pragma unroll
    for (int i = 0; i < 2; ++i) {
        int g = t + i * 256;
        int row = g >> 3, colg = (g & 7) * 8;
        *(half8*)&sA[row][colg] = *(const half8*)(A0 + (size_t)row * 512 + colg);
    }
    __syncthreads();
    f32x4 acc[4][8] = {};
    int arow = l & 15, kg = (l >> 4) << 3;
#pragma unroll
    for (int kk = 0; kk < 64; kk += 32) {
        half8 a[4], bb[8];
#pragma unroll
        for (int mt = 0; mt < 4; ++mt) a[mt] = *(const half8*)&sA[mt * 16 + arow][kk + kg];
#pragma unroll
        for (int nt = 0; nt < 8; ++nt) {
            int col = (w << 7) + nt * 16 + arow;
            bb[nt] = *(const half8*)(B0 + (size_t)col * 64 + kk + kg);
        }
#pragma unroll
        for (int mt = 0; mt < 4; ++mt)
#pragma unroll
            for (int nt = 0; nt < 8; ++nt)
                acc[mt][nt] = __builtin_amdgcn_mfma_f32_16x16x32_f16(a[mt], bb[nt], acc[mt][nt], 0, 0, 0);
    }
    if (outT) {
#pragma unroll
        for (int mt = 0; mt < 4; ++mt)
#pragma unroll
            for (int nt = 0; nt < 8; ++nt) {
                int col = (h << 9) + (w << 7) + nt * 16 + arow;
                int row0 = rb * 64 + mt * 16 + ((l >> 4) << 2);
                half4v v4;
#pragma unroll
                for (int v = 0; v < 4; ++v) v4[v] = (_Float16)acc[mt][nt][v];
                *(half4v*)(C + (size_t)col * 512 + row0) = v4;
            }
    } else {
        _Float16* C0 = C + (size_t)rb * 64 * 4096 + h * 512;
#pragma unroll
        for (int mt = 0; mt < 4; ++mt)
#pragma unroll
            for (int nt = 0; nt < 8; ++nt)
#pragma unroll
                for (int v = 0; v < 4; ++v) {
                    int row = mt * 16 + ((l >> 4) << 2) + v;
                    int col = (w << 7) + nt * 16 + arow;
                    C0[(size_t)row * 4096 + col] = (_Float16)acc[mt][nt][v];
                }
    }
}

// ---------------- U = query @ WcT^T + bu  (2048x4096 f16), grid (32,16) ----------------
__global__ __launch_bounds__(256) void k_gemmU(
    const _Float16* __restrict__ A, const _Float16* __restrict__ B,
    const float* __restrict__ bu, _Float16* __restrict__ U)
{
    __shared__ __align__(16) _Float16 sA[64][520];
    int q0 = blockIdx.x * 64;
    int t = threadIdx.x, w = t >> 6, l = t & 63;
    int colb = blockIdx.y * 256 + w * 64;
    const _Float16* Ab = A + (size_t)q0 * 512;
#pragma unroll
    for (int i = 0; i < 16; ++i) {
        int e = i * 2048 + t * 8;
        *(half8*)&sA[e >> 9][e & 511] = *(const half8*)(Ab + e);
    }
    __syncthreads();
    f32x4 acc[4][4] = {};
    int arow = l & 15, kg = (l >> 4) << 3;
#pragma unroll 2
    for (int kk = 0; kk < 512; kk += 32) {
        half8 a[4], bb[4];
#pragma unroll
        for (int mt = 0; mt < 4; ++mt) a[mt] = *(const half8*)&sA[mt * 16 + arow][kk + kg];
#pragma unroll
        for (int nt = 0; nt < 4; ++nt)
            bb[nt] = *(const half8*)(B + (size_t)(colb + nt * 16 + arow) * 512 + kk + kg);
#pragma unroll
        for (int mt = 0; mt < 4; ++mt)
#pragma unroll
            for (int nt = 0; nt < 4; ++nt)
                acc[mt][nt] = __builtin_amdgcn_mfma_f32_16x16x32_f16(a[mt], bb[nt], acc[mt][nt], 0, 0, 0);
    }
#pragma unroll
    for (int mt = 0; mt < 4; ++mt)
#pragma unroll
        for (int nt = 0; nt < 4; ++nt)
#pragma unroll
            for (int v = 0; v < 4; ++v) {
                int row = q0 + mt * 16 + ((l >> 4) << 2) + v;
                int col = colb + nt * 16 + arow;
                U[(size_t)row * 4096 + col] = (_Float16)(acc[mt][nt][v] + bu[col]);
            }
}

// ---------------- main: per-q key tile -> MFMA scores -> softmax -> g ----------------
__global__ __launch_bounds__(512, 4) void k_main(
    const _Float16* __restrict__ Zr, const float* __restrict__ r,
    const float* __restrict__ w1, const float* __restrict__ b1,
    const _Float16* __restrict__ U, _Float16* __restrict__ G)
{
    __shared__ __align__(16) _Float16 sKey[64][520];
    __shared__ __align__(16) _Float16 sU[8][520];
    __shared__ float sP[512];

    int q = blockIdx.x;
    int t = threadIdx.x, w = t >> 6, l = t & 63;
    int ch = q >> 3, s8 = q & 7;

    // Z-part of key: one contiguous 32KB chunk. dest sKey[e>>8][e&255]
    const _Float16* src = Zr + ((size_t)ch * 2048 + s8 * 256) * 64;
#pragma unroll
    for (int i = 0; i < 4; ++i) {
        int e = i * 4096 + t * 8;
        *(half8*)&sKey[e >> 8][e & 255] = *(const half8*)(src + e);
    }
    // u[q]: 4096 f16
    {
        int e = t * 8;
        *(half8*)&sU[e >> 9][e & 511] = *(const half8*)(U + (size_t)q * 4096 + e);
    }
    // r_proj: thread -> (half=t>>8, m=t&255), 32 k's each
    {
        int m = t & 255, half = t >> 8;
        float w10 = w1[2 * m], w11 = w1[2 * m + 1], b1m = b1[m];
        const float2* r2q = (const float2*)r + (size_t)q * 64;
#pragma unroll 8
        for (int i = 0; i < 32; ++i) {
            int k = half * 32 + i;
            float2 rv = r2q[k];
            sKey[k][256 + m] = (_Float16)(rv.x * w10 + rv.y * w11 + b1m);
        }
    }
    __syncthreads();

    // scores via MFMA: S[krow][h] = sum_j key[krow][j]*u[h][j]; waves 0..3, M-tile w*16
    if (w < 4) {
        f32x4 acc = {};
        int arow = l & 15, kg = (l >> 4) << 3;
        const _Float16* ar = &sKey[w * 16 + arow][kg];
        const _Float16* br = &sU[l & 7][kg];
#pragma unroll 4
        for (int kk = 0; kk < 512; kk += 32)
            acc = __builtin_amdgcn_mfma_f32_16x16x32_f16(
                *(const half8*)(ar + kk), *(const half8*)(br + kk), acc, 0, 0, 0);
        if ((l & 15) < 8) {
            int h = l & 15, krow0 = w * 16 + ((l >> 4) << 2);
#pragma unroll
            for (int v = 0; v < 4; ++v) sP[(h << 6) + krow0 + v] = acc[v];
        }
    }
    __syncthreads();

    // softmax per head (wave == head)
    {
        float v = sP[t];
        float mx = v;
#pragma unroll
        for (int mm = 1; mm < 64; mm <<= 1) mx = fmaxf(mx, __shfl_xor(mx, mm, 64));
        float e = __expf(v - mx);
        float sm = e;
#pragma unroll
        for (int mm = 1; mm < 64; mm <<= 1) sm += __shfl_xor(sm, mm, 64);
        sP[t] = e / sm;
    }
    __syncthreads();

    // g[h=w][l*8..+8] = sum_k attn[h,k] * key[k][l*8..]
    {
        const float* attn = &sP[w << 6];
        float g8[8] = {};
#pragma unroll 8
        for (int k = 0; k < 64; ++k) {
            half8 kv = *(const half8*)&sKey[k][l * 8];
            float a = attn[k];
#pragma unroll
            for (int x = 0; x < 8; ++x) g8[x] += a * (float)kv[x];
        }
        half8 go;
#pragma unroll
        for (int x = 0; x < 8; ++x) go[x] = (_Float16)g8[x];
        *(half8*)(G + (size_t)q * 4096 + t * 8) = go;
    }
}

// ---------------- final: out[:,256+cb*64 ..] = G @ Mt^T + b_eff; grid (32,8) ----------------
__global__ __launch_bounds__(256) void k_final(
    const _Float16* __restrict__ G, const _Float16* __restrict__ Mt,
    const float* __restrict__ b_eff, const float* __restrict__ qz,
    float* __restrict__ out)
{
    __shared__ __align__(16) _Float16 sA[64][520];
    int rb = blockIdx.x, cb = blockIdx.y;
    int q0 = rb * 64;
    int t = threadIdx.x, w = t >> 6, l = t & 63;

    if (cb == 0) {
#pragma unroll
        for (int i = 0; i < 16; ++i) {
            int idx4 = i * 256 + t;
            int row = idx4 >> 6, c = (idx4 & 63) << 2;
            *(float4*)&out[(size_t)(q0 + row) * 768 + c] =
                *(const float4*)&qz[(size_t)(q0 + row) * 256 + c];
        }
    }

    f32x4 acc[4] = {};
    int arow = l & 15, kg = (l >> 4) << 3;
    int ecol = cb * 64 + w * 16 + arow;
    const _Float16* Brow = Mt + (size_t)ecol * 4096;
    for (int c = 0; c < 8; ++c) {
#pragma unroll
        for (int i = 0; i < 16; ++i) {
            int e = i * 2048 + t * 8;
            *(half8*)&sA[e >> 9][e & 511] = *(const half8*)(G + (size_t)(q0 + (e >> 9)) * 4096 + c * 512 + (e & 511));
        }
        __syncthreads();
#pragma unroll 4
        for (int kk = 0; kk < 512; kk += 32) {
            half8 bb = *(const half8*)(Brow + c * 512 + kk + kg);
#pragma unroll
            for (int mt = 0; mt < 4; ++mt) {
                half8 a = *(const half8*)&sA[mt * 16 + arow][kk + kg];
                acc[mt] = __builtin_amdgcn_mfma_f32_16x16x32_f16(a, bb, acc[mt], 0, 0, 0);
            }
        }
        __syncthreads();
    }
#pragma unroll
    for (int mt = 0; mt < 4; ++mt)
#pragma unroll
        for (int v = 0; v < 4; ++v) {
            int row = q0 + mt * 16 + ((l >> 4) << 2) + v;
            out[(size_t)row * 768 + 256 + ecol] = acc[mt][v] + b_eff[ecol];
        }
}

extern "C" void kernel_launch(void* const* d_in, const int* in_sizes, int n_in,
                              void* d_out, int out_size, void* d_ws, size_t ws_size,
                              hipStream_t stream) {
    const float* Z          = (const float*)d_in[0];
    const float* Qm         = (const float*)d_in[1];
    const float* q_z        = (const float*)d_in[2];
    const float* r          = (const float*)d_in[3];
    const float* w1         = (const float*)d_in[4];
    const float* b1         = (const float*)d_in[5];
    const float* w2         = (const float*)d_in[6];
    const float* b2         = (const float*)d_in[7];
    const float* in_proj_w  = (const float*)d_in[8];
    const float* in_proj_b  = (const float*)d_in[9];
    const float* out_proj_w = (const float*)d_in[10];
    const float* out_proj_b = (const float*)d_in[11];
    float* out = (float*)d_out;

    _Float16* wsh = (_Float16*)d_ws;
    _Float16* wqT   = wsh + O_WQT;
    _Float16* wkT   = wsh + O_WKT;
    _Float16* wvT   = wsh + O_WVT;
    _Float16* wo    = wsh + O_WO;
    _Float16* query = wsh + O_QRY;
    _Float16* WcT   = wsh + O_WCT;
    _Float16* Mt    = wsh + O_MT;
    _Float16* U     = wsh + O_U;
    _Float16* G     = wsh + O_G;
    _Float16* Zt    = wsh + O_ZT;
    _Float16* Zr    = wsh + O_ZR;
    float*    bu    = (float*)(wsh + O_F32);
    float*    b_eff = bu + 4096;

    k_prep<<<8210, 256, 0, stream>>>(in_proj_w, out_proj_w, q_z, Qm, w2, b2,
                                     in_proj_b, out_proj_b, wsh, bu, b_eff);
    k_zt<<<dim3(256, 4), 256, 0, stream>>>(Z, Zt);
    k_small<<<dim3(8, 8), 256, 0, stream>>>(wqT, wkT, WcT, 1);
    k_small<<<dim3(8, 8), 256, 0, stream>>>(wo, wvT, Mt, 0);
    k_gemmU<<<dim3(32, 16), 256, 0, stream>>>(query, WcT, bu, U);
    k_passA<<<4096, 256, 0, stream>>>(Zt, r, Zr);
    k_main<<<2048, 512, 0, stream>>>(Zr, r, w1, b1, U, G);
    k_final<<<dim3(32, 8), 256, 0, stream>>>(G, Mt, b_eff, q_z, out);
}

// Round 4
// 312.737 us; speedup vs baseline: 2.1378x; 1.0276x over previous
//
#include <hip/hip_runtime.h>

// FeatureAggregation, round 4: MFMA g-phase, LDS-tiled weight transposes,
// dword gather loads, bigger k_final tiles.
// Pipeline:
//   k_prep  : query matrix, wo copy, bu, b_eff (all coalesced)
//   k_tw    : LDS-tiled transposes -> wqT, wkT(*0.125), wvT
//   k_zt    : Z [c][x][y] f32 -> Zt [x][y][c] f16
//   k_small : WcT = (wqT @ wkT)^T  and  Mt = wo @ wvT
//   k_gemmU : U = query @ WcT^T + bu
//   k_passA : bilinear interp, channel-contiguous -> Zr[ch][qp][col]
//   k_main  : per-q: key tile -> MFMA scores -> softmax -> MFMA g -> G
//   k_final : out[:,256:768] = G @ Mt^T + b_eff (64x128 tiles), out[:,0:256] = q_z

typedef _Float16 half8 __attribute__((ext_vector_type(8)));
typedef _Float16 half2v __attribute__((ext_vector_type(2)));
typedef float f32x4 __attribute__((ext_vector_type(4)));

// ---------------- ws element offsets (f16 units) ----------------
#define O_WQT   0u          // 512*512
#define O_WKT   262144u     // [8][512][64] * 0.125
#define O_WVT   524288u     // [8][512][64]
#define O_WO    786432u     // 512*512
#define O_QRY   1048576u    // 2048*512
#define O_WCT   2097152u    // [4096][512]
#define O_MT    4194304u    // [512][4096]
#define O_U     6291456u    // 2048*4096
#define O_G     14680064u   // 2048*4096
#define O_ZT    23068672u   // 256*256*256
#define O_ZR    39845888u   // 256*2048*64
#define O_F32   73400320u   // f32 region (bu 4096, b_eff 512)

// ---------------- prep: query, wo, bu, b_eff ----------------
__global__ __launch_bounds__(256) void k_prep(
    const float* __restrict__ ipw, const float* __restrict__ opw,
    const float* __restrict__ q_z, const float* __restrict__ Qm,
    const float* __restrict__ w2, const float* __restrict__ b2,
    const float* __restrict__ ipb, const float* __restrict__ opb,
    _Float16* __restrict__ wsh, float* __restrict__ bu, float* __restrict__ b_eff)
{
    int idx = blockIdx.x * 256 + threadIdx.x;
    if (idx < 1048576) {                       // query
        int q = idx >> 9, j = idx & 511;
        float v;
        if (j < 256) v = q_z[q * 256 + j];
        else {
            int m = j - 256;
            v = Qm[q * 3] * w2[m * 3] + Qm[q * 3 + 1] * w2[m * 3 + 1]
              + Qm[q * 3 + 2] * w2[m * 3 + 2] + b2[m];
        }
        wsh[O_QRY + idx] = (_Float16)v;
    } else if (idx < 1310720) {                // wo straight copy
        int e0 = idx - 1048576;
        wsh[O_WO + e0] = (_Float16)opw[e0];
    } else if (idx < 1314816) {                // bu[c]
        int c = idx - 1310720;
        int h = c >> 9, j = c & 511;
        float s = 0.f;
        for (int d = 0; d < 64; ++d)
            s += ipb[512 + (h << 6) + d] * ipw[(size_t)(512 + (h << 6) + d) * 512 + j];
        bu[c] = 0.125f * s;
    } else if (idx < 1315328) {                // b_eff[e]
        int e = idx - 1314816;
        float s = opb[e];
        const float* worow = opw + (size_t)e * 512;
        for (int n = 0; n < 512; ++n) s += ipb[1024 + n] * worow[n];
        b_eff[e] = s;
    }
}

// ---------------- weight transposes via LDS tiles ----------------
// sec0: wqT[i][e] = ipw[e*512+i]          (512x512 transpose)
// sec1: wkT[h][j][d] = 0.125*ipw[(512+h*64+d)*512+j]
// sec2: wvT[h][j][d] =       ipw[(1024+h*64+d)*512+j]
__global__ __launch_bounds__(256) void k_tw(
    const float* __restrict__ ipw, _Float16* __restrict__ wsh)
{
    __shared__ float sT[64][65];
    int bx = blockIdx.x;
    int sec = bx >> 6, tile = bx & 63;
    int t = threadIdx.x;
    int th = tile >> 3, tl = tile & 7;
    int row0, col0;
    if (sec == 0) { row0 = tl * 64;             col0 = th * 64; }
    else          { row0 = 512 * sec + th * 64; col0 = tl * 64; }
    const float* src = ipw + (size_t)row0 * 512 + col0;
#pragma unroll
    for (int i = 0; i < 4; ++i) {
        int rr = i * 16 + (t >> 4), cc = (t & 15) * 4;
        float4 v = *(const float4*)(src + (size_t)rr * 512 + cc);
        sT[rr][cc] = v.x; sT[rr][cc + 1] = v.y; sT[rr][cc + 2] = v.z; sT[rr][cc + 3] = v.w;
    }
    __syncthreads();
    float scale = (sec == 1) ? 0.125f : 1.0f;
#pragma unroll
    for (int it = 0; it < 2; ++it) {
        int g = t + it * 256;
        int a = g >> 3, b8 = (g & 7) * 8;
        half8 o;
#pragma unroll
        for (int j = 0; j < 8; ++j) o[j] = (_Float16)(scale * sT[b8 + j][a]);
        size_t dst;
        if (sec == 0)      dst = O_WQT + (size_t)(th * 64 + a) * 512 + tl * 64 + b8;
        else if (sec == 1) dst = O_WKT + (size_t)th * 32768 + (size_t)(tl * 64 + a) * 64 + b8;
        else               dst = O_WVT + (size_t)th * 32768 + (size_t)(tl * 64 + a) * 64 + b8;
        *(half8*)(wsh + dst) = o;
    }
}

// ---------------- Z transpose: [c][x][y] f32 -> Zt[x][y][c] f16 ----------------
__global__ __launch_bounds__(256) void k_zt(
    const float* __restrict__ Z, _Float16* __restrict__ Zt)
{
    __shared__ float sT[256][67];
    int x = blockIdx.x, yt = blockIdx.y * 64;
    int t = threadIdx.x;
#pragma unroll
    for (int i = 0; i < 16; ++i) {
        int c = i * 16 + (t >> 4), y = (t & 15) * 4;
        float4 v = *(const float4*)(Z + (size_t)c * 65536 + x * 256 + yt + y);
        sT[c][y] = v.x; sT[c][y + 1] = v.y; sT[c][y + 2] = v.z; sT[c][y + 3] = v.w;
    }
    __syncthreads();
    _Float16* outb = Zt + ((size_t)(x * 256 + yt)) * 256 + t;
#pragma unroll 8
    for (int y = 0; y < 64; ++y)
        outb[(size_t)y * 256] = (_Float16)sT[t][y];
}

// ---------------- pass A: interp -> Zr[ch][qp][col], dword channel loads ----------------
__global__ __launch_bounds__(256, 4) void k_passA(
    const _Float16* __restrict__ Zt, const float* __restrict__ r,
    _Float16* __restrict__ Zr)
{
    __shared__ float sT[256][33];
    int b = blockIdx.x;
    int t = threadIdx.x, w = t >> 6, l = t & 63;
    const float2* r2 = (const float2*)r;
#pragma unroll 2
    for (int i = 0; i < 8; ++i) {
        int ptl = w * 8 + i;
        float2 rv = r2[b * 32 + ptl];
        int x1 = (int)rv.x, y1 = (int)rv.y;
        float dx = rv.x - (float)x1, dy = rv.y - (float)y1;
        float w11 = (1.f - dx) * (1.f - dy), w21 = dx * (1.f - dy);
        float w12 = (1.f - dx) * dy,         w22 = dx * dy;
        const _Float16* base = Zt + ((size_t)(x1 * 256 + y1)) * 256;
#pragma unroll
        for (int cg = 0; cg < 2; ++cg) {
            int c = cg * 128 + l * 2;
            half2v z11 = *(const half2v*)(base + c);
            half2v z12 = *(const half2v*)(base + 256 + c);
            half2v z21 = *(const half2v*)(base + 65536 + c);
            half2v z22 = *(const half2v*)(base + 65536 + 256 + c);
            sT[c][ptl]     = w11 * (float)z11[0] + w21 * (float)z21[0]
                           + w12 * (float)z12[0] + w22 * (float)z22[0];
            sT[c + 1][ptl] = w11 * (float)z11[1] + w21 * (float)z21[1]
                           + w12 * (float)z12[1] + w22 * (float)z22[1];
        }
    }
    __syncthreads();
    int ch0 = t >> 2, colc = (t & 3) * 8;
#pragma unroll
    for (int g = 0; g < 4; ++g) {
        int ch = g * 64 + ch0;
        half8 o;
#pragma unroll
        for (int j = 0; j < 8; ++j) o[j] = (_Float16)sT[ch][colc + j];
        *(half8*)(Zr + (size_t)ch * 131072 + b * 32 + colc) = o;
    }
}

// ---- small GEMM: C = A[rb*64.., h*64..](64xK64) @ BT_h(512x64)^T ----
__global__ __launch_bounds__(256) void k_small(
    const _Float16* __restrict__ A, const _Float16* __restrict__ BT,
    _Float16* __restrict__ C, int outT)
{
    __shared__ __align__(16) _Float16 sA[64][72];
    int rb = blockIdx.x, h = blockIdx.y;
    int t = threadIdx.x, w = t >> 6, l = t & 63;
    const _Float16* A0 = A + (size_t)rb * 64 * 512 + h * 64;
    const _Float16* B0 = BT + (size_t)h * 512 * 64;
#pragma unroll
    for (int i = 0; i < 2; ++i) {
        int g = t + i * 256;
        int row = g >> 3, colg = (g & 7) * 8;
        *(half8*)&sA[row][colg] = *(const half8*)(A0 + (size_t)row * 512 + colg);
    }
    __syncthreads();
    f32x4 acc[4][8] = {};
    int arow = l & 15, kg = (l >> 4) << 3;
#pragma unroll
    for (int kk = 0; kk < 64; kk += 32) {
        half8 a[4], bb[8];
#pragma unroll
        for (int mt = 0; mt < 4; ++mt) a[mt] = *(const half8*)&sA[mt * 16 + arow][kk + kg];
#pragma unroll
        for (int nt = 0; nt < 8; ++nt) {
            int col = (w << 7) + nt * 16 + arow;
            bb[nt] = *(const half8*)(B0 + (size_t)col * 64 + kk + kg);
        }
#pragma unroll
        for (int mt = 0; mt < 4; ++mt)
#pragma unroll
            for (int nt = 0; nt < 8; ++nt)
                acc[mt][nt] = __builtin_amdgcn_mfma_f32_16x16x32_f16(a[mt], bb[nt], acc[mt][nt], 0, 0, 0);
    }
    if (outT) {
#pragma unroll
        for (int mt = 0; mt < 4; ++mt)
#pragma unroll
            for (int nt = 0; nt < 8; ++nt) {
                int col = (h << 9) + (w << 7) + nt * 16 + arow;
                int row0 = rb * 64 + mt * 16 + ((l >> 4) << 2);
#pragma unroll
                for (int v = 0; v < 4; ++v)
                    C[(size_t)col * 512 + row0 + v] = (_Float16)acc[mt][nt][v];
            }
    } else {
        _Float16* C0 = C + (size_t)rb * 64 * 4096 + h * 512;
#pragma unroll
        for (int mt = 0; mt < 4; ++mt)
#pragma unroll
            for (int nt = 0; nt < 8; ++nt)
#pragma unroll
                for (int v = 0; v < 4; ++v) {
                    int row = mt * 16 + ((l >> 4) << 2) + v;
                    int col = (w << 7) + nt * 16 + arow;
                    C0[(size_t)row * 4096 + col] = (_Float16)acc[mt][nt][v];
                }
    }
}

// ---------------- U = query @ WcT^T + bu  (2048x4096 f16), grid (32,16) ----------------
__global__ __launch_bounds__(256) void k_gemmU(
    const _Float16* __restrict__ A, const _Float16* __restrict__ B,
    const float* __restrict__ bu, _Float16* __restrict__ U)
{
    __shared__ __align__(16) _Float16 sA[64][520];
    int q0 = blockIdx.x * 64;
    int t = threadIdx.x, w = t >> 6, l = t & 63;
    int colb = blockIdx.y * 256 + w * 64;
    const _Float16* Ab = A + (size_t)q0 * 512;
#pragma unroll
    for (int i = 0; i < 16; ++i) {
        int e = i * 2048 + t * 8;
        *(half8*)&sA[e >> 9][e & 511] = *(const half8*)(Ab + e);
    }
    __syncthreads();
    f32x4 acc[4][4] = {};
    int arow = l & 15, kg = (l >> 4) << 3;
#pragma unroll 2
    for (int kk = 0; kk < 512; kk += 32) {
        half8 a[4], bb[4];
#pragma unroll
        for (int mt = 0; mt < 4; ++mt) a[mt] = *(const half8*)&sA[mt * 16 + arow][kk + kg];
#pragma unroll
        for (int nt = 0; nt < 4; ++nt)
            bb[nt] = *(const half8*)(B + (size_t)(colb + nt * 16 + arow) * 512 + kk + kg);
#pragma unroll
        for (int mt = 0; mt < 4; ++mt)
#pragma unroll
            for (int nt = 0; nt < 4; ++nt)
                acc[mt][nt] = __builtin_amdgcn_mfma_f32_16x16x32_f16(a[mt], bb[nt], acc[mt][nt], 0, 0, 0);
    }
#pragma unroll
    for (int mt = 0; mt < 4; ++mt)
#pragma unroll
        for (int nt = 0; nt < 4; ++nt)
#pragma unroll
            for (int v = 0; v < 4; ++v) {
                int row = q0 + mt * 16 + ((l >> 4) << 2) + v;
                int col = colb + nt * 16 + arow;
                U[(size_t)row * 4096 + col] = (_Float16)(acc[mt][nt][v] + bu[col]);
            }
}

// ---------------- main: key tile -> MFMA scores -> softmax -> MFMA g ----------------
__global__ __launch_bounds__(512, 2) void k_main(
    const _Float16* __restrict__ Zr, const float* __restrict__ r,
    const float* __restrict__ w1, const float* __restrict__ b1,
    const _Float16* __restrict__ U, _Float16* __restrict__ G)
{
    __shared__ __align__(16) _Float16 sKey[64][520];
    __shared__ __align__(16) _Float16 sU[8][520];     // u[q]; reused as sG after scores
    __shared__ float sP[512];
    __shared__ __align__(16) _Float16 sA16[16][72];   // attn in A-fragment layout

    int q = blockIdx.x;
    int t = threadIdx.x, w = t >> 6, l = t & 63;
    int ch = q >> 3, s8 = q & 7;

    // zero sA16 (rows 8-15 feed MFMA as zeros)
    for (int i = t; i < 576; i += 512) ((unsigned*)sA16)[i] = 0u;

    // Z-part of key: contiguous 32KB
    const _Float16* src = Zr + ((size_t)ch * 2048 + s8 * 256) * 64;
#pragma unroll
    for (int i = 0; i < 4; ++i) {
        int e = i * 4096 + t * 8;
        *(half8*)&sKey[e >> 8][e & 255] = *(const half8*)(src + e);
    }
    // u[q]
    {
        int e = t * 8;
        *(half8*)&sU[e >> 9][e & 511] = *(const half8*)(U + (size_t)q * 4096 + e);
    }
    // r_proj
    {
        int m = t & 255, half = t >> 8;
        float w10 = w1[2 * m], w11 = w1[2 * m + 1], b1m = b1[m];
        const float2* r2q = (const float2*)r + (size_t)q * 64;
#pragma unroll 8
        for (int i = 0; i < 32; ++i) {
            int k = half * 32 + i;
            float2 rv = r2q[k];
            sKey[k][256 + m] = (_Float16)(rv.x * w10 + rv.y * w11 + b1m);
        }
    }
    __syncthreads();

    // scores via MFMA: S[k][h], waves 0..3
    if (w < 4) {
        f32x4 acc = {};
        int arow = l & 15, kg = (l >> 4) << 3;
        const _Float16* ar = &sKey[w * 16 + arow][kg];
        const _Float16* br = &sU[l & 7][kg];
#pragma unroll 4
        for (int kk = 0; kk < 512; kk += 32)
            acc = __builtin_amdgcn_mfma_f32_16x16x32_f16(
                *(const half8*)(ar + kk), *(const half8*)(br + kk), acc, 0, 0, 0);
        if ((l & 15) < 8) {
            int h = l & 15, krow0 = w * 16 + ((l >> 4) << 2);
#pragma unroll
            for (int v = 0; v < 4; ++v) sP[(h << 6) + krow0 + v] = acc[v];
        }
    }
    __syncthreads();

    // softmax per head (wave == head); store attn f16 in A-frag layout
    {
        float v = sP[t];
        float mx = v;
#pragma unroll
        for (int mm = 1; mm < 64; mm <<= 1) mx = fmaxf(mx, __shfl_xor(mx, mm, 64));
        float e = __expf(v - mx);
        float sm = e;
#pragma unroll
        for (int mm = 1; mm < 64; mm <<= 1) sm += __shfl_xor(sm, mm, 64);
        sA16[w][l] = (_Float16)(e / sm);
    }
    __syncthreads();

    // g = attn @ key via MFMA; wave w covers cols [w*64, w*64+64)
    {
        f32x4 acc[4] = {};
        int arow = l & 15, kq = (l >> 4) << 3;
        half8 a0 = *(const half8*)&sA16[arow][kq];
        half8 a1 = *(const half8*)&sA16[arow][32 + kq];
#pragma unroll
        for (int nt = 0; nt < 4; ++nt) {
            int n0 = (w << 6) + (nt << 4);
            half8 b0, b1f;
#pragma unroll
            for (int jj = 0; jj < 8; ++jj) b0[jj] = sKey[kq + jj][n0 + arow];
            acc[nt] = __builtin_amdgcn_mfma_f32_16x16x32_f16(a0, b0, acc[nt], 0, 0, 0);
#pragma unroll
            for (int jj = 0; jj < 8; ++jj) b1f[jj] = sKey[32 + kq + jj][n0 + arow];
            acc[nt] = __builtin_amdgcn_mfma_f32_16x16x32_f16(a1, b1f, acc[nt], 0, 0, 0);
        }
        if (l < 32) {
            int rgrp = (l >> 4) << 2;
#pragma unroll
            for (int nt = 0; nt < 4; ++nt) {
                int n0 = (w << 6) + (nt << 4);
#pragma unroll
                for (int v = 0; v < 4; ++v)
                    sU[rgrp + v][n0 + arow] = (_Float16)acc[nt][v];
            }
        }
    }
    __syncthreads();

    // coalesced G write from sG(=sU)
    {
        int c = t * 8;
        *(half8*)(G + (size_t)q * 4096 + c) = *(const half8*)&sU[c >> 9][c & 511];
    }
}

// ---------------- final: 64x128 tiles, grid (32,4) ----------------
__global__ __launch_bounds__(256) void k_final(
    const _Float16* __restrict__ G, const _Float16* __restrict__ Mt,
    const float* __restrict__ b_eff, const float* __restrict__ qz,
    float* __restrict__ out)
{
    __shared__ __align__(16) _Float16 sA[64][520];
    int rb = blockIdx.x, cb = blockIdx.y;
    int q0 = rb * 64;
    int t = threadIdx.x, w = t >> 6, l = t & 63;

    if (cb == 0) {
#pragma unroll
        for (int i = 0; i < 16; ++i) {
            int idx4 = i * 256 + t;
            int row = idx4 >> 6, c = (idx4 & 63) << 2;
            *(float4*)&out[(size_t)(q0 + row) * 768 + c] =
                *(const float4*)&qz[(size_t)(q0 + row) * 256 + c];
        }
    }

    f32x4 acc[4][2] = {};
    int arow = l & 15, kg = (l >> 4) << 3;
    int e0 = cb * 128 + (w << 5);
    for (int c = 0; c < 8; ++c) {
#pragma unroll
        for (int i = 0; i < 16; ++i) {
            int e = i * 2048 + t * 8;
            *(half8*)&sA[e >> 9][e & 511] =
                *(const half8*)(G + (size_t)(q0 + (e >> 9)) * 4096 + c * 512 + (e & 511));
        }
        __syncthreads();
#pragma unroll 4
        for (int kk = 0; kk < 512; kk += 32) {
            half8 a[4], bb[2];
#pragma unroll
            for (int nt = 0; nt < 2; ++nt)
                bb[nt] = *(const half8*)(Mt + (size_t)(e0 + nt * 16 + arow) * 4096 + c * 512 + kk + kg);
#pragma unroll
            for (int mt = 0; mt < 4; ++mt) {
                a[mt] = *(const half8*)&sA[mt * 16 + arow][kk + kg];
#pragma unroll
                for (int nt = 0; nt < 2; ++nt)
                    acc[mt][nt] = __builtin_amdgcn_mfma_f32_16x16x32_f16(a[mt], bb[nt], acc[mt][nt], 0, 0, 0);
            }
        }
        __syncthreads();
    }
#pragma unroll
    for (int mt = 0; mt < 4; ++mt)
#pragma unroll
        for (int nt = 0; nt < 2; ++nt)
#pragma unroll
            for (int v = 0; v < 4; ++v) {
                int row = q0 + mt * 16 + ((l >> 4) << 2) + v;
                int ecol = e0 + nt * 16 + arow;
                out[(size_t)row * 768 + 256 + ecol] = acc[mt][nt][v] + b_eff[ecol];
            }
}

extern "C" void kernel_launch(void* const* d_in, const int* in_sizes, int n_in,
                              void* d_out, int out_size, void* d_ws, size_t ws_size,
                              hipStream_t stream) {
    const float* Z          = (const float*)d_in[0];
    const float* Qm         = (const float*)d_in[1];
    const float* q_z        = (const float*)d_in[2];
    const float* r          = (const float*)d_in[3];
    const float* w1         = (const float*)d_in[4];
    const float* b1         = (const float*)d_in[5];
    const float* w2         = (const float*)d_in[6];
    const float* b2         = (const float*)d_in[7];
    const float* in_proj_w  = (const float*)d_in[8];
    const float* in_proj_b  = (const float*)d_in[9];
    const float* out_proj_w = (const float*)d_in[10];
    const float* out_proj_b = (const float*)d_in[11];
    float* out = (float*)d_out;

    _Float16* wsh = (_Float16*)d_ws;
    _Float16* wqT   = wsh + O_WQT;
    _Float16* wkT   = wsh + O_WKT;
    _Float16* wvT   = wsh + O_WVT;
    _Float16* wo    = wsh + O_WO;
    _Float16* query = wsh + O_QRY;
    _Float16* WcT   = wsh + O_WCT;
    _Float16* Mt    = wsh + O_MT;
    _Float16* U     = wsh + O_U;
    _Float16* G     = wsh + O_G;
    _Float16* Zt    = wsh + O_ZT;
    _Float16* Zr    = wsh + O_ZR;
    float*    bu    = (float*)(wsh + O_F32);
    float*    b_eff = bu + 4096;

    k_prep<<<5138, 256, 0, stream>>>(in_proj_w, out_proj_w, q_z, Qm, w2, b2,
                                     in_proj_b, out_proj_b, wsh, bu, b_eff);
    k_tw<<<192, 256, 0, stream>>>(in_proj_w, wsh);
    k_zt<<<dim3(256, 4), 256, 0, stream>>>(Z, Zt);
    k_small<<<dim3(8, 8), 256, 0, stream>>>(wqT, wkT, WcT, 1);
    k_small<<<dim3(8, 8), 256, 0, stream>>>(wo, wvT, Mt, 0);
    k_gemmU<<<dim3(32, 16), 256, 0, stream>>>(query, WcT, bu, U);
    k_passA<<<4096, 256, 0, stream>>>(Zt, r, Zr);
    k_main<<<2048, 512, 0, stream>>>(Zr, r, w1, b1, U, G);
    k_final<<<dim3(32, 4), 256, 0, stream>>>(G, Mt, b_eff, q_z, out);
}

// Round 5
// 281.373 us; speedup vs baseline: 2.3761x; 1.1115x over previous
//
#include <hip/hip_runtime.h>

// FeatureAggregation, round 5: 5-launch pipeline (was 9), parallel b_eff,
// split-K scores in k_main, K-split gemmU sharing one merged launch with passA.
// Pipeline:
//   k_pre    : zt transpose + weight transposes + query/wo build + bu + b_eff
//   k_small2 : WcT = (wqT @ wkT)^T  and  Mt = wo @ wvT     (one launch)
//   k_mid    : gemmU (U = query @ WcT^T + bu)  +  passA (bilinear -> Zr)
//   k_main   : per-q: key tile -> MFMA scores (8 waves, split-K) -> softmax -> MFMA g
//   k_final  : out[:,256:768] = G @ Mt^T + b_eff ; out[:,0:256] = q_z
//
// key index fact (reference's raw reshape):
//   key[q,k,j<256] = bilinear(Z[q>>3], r[256*(q&7) + 4k + (j>>6), j&63])
//   key[q,k,256+m] = r[q,k,:] . w1[m,:] + b1[m]

typedef _Float16 half8 __attribute__((ext_vector_type(8)));
typedef _Float16 half4v __attribute__((ext_vector_type(4)));
typedef _Float16 half2v __attribute__((ext_vector_type(2)));
typedef float f32x4 __attribute__((ext_vector_type(4)));

// ---------------- ws element offsets (f16 units) ----------------
#define O_WQT   0u          // 512*512
#define O_WKT   262144u     // [8][512][64] * 0.125
#define O_WVT   524288u     // [8][512][64]
#define O_WO    786432u     // 512*512
#define O_QRY   1048576u    // 2048*512
#define O_WCT   2097152u    // [4096][512]
#define O_MT    4194304u    // [512][4096]
#define O_U     6291456u    // 2048*4096
#define O_G     14680064u   // 2048*4096
#define O_ZT    23068672u   // 256*256*256
#define O_ZR    39845888u   // 256*2048*64
#define O_F32   73400320u   // f32 region (bu 4096, b_eff 512)

// ---------------- k_pre: all input preprocessing in one launch ----------------
// block map: [0,2048) zt | [2048,2240) tw | [2240,3264) query | [3264,3520) wo
//            [3520,3536) bu | [3536,3664) b_eff
__global__ __launch_bounds__(256) void k_pre(
    const float* __restrict__ Z, const float* __restrict__ ipw,
    const float* __restrict__ opw, const float* __restrict__ q_z,
    const float* __restrict__ Qm, const float* __restrict__ w2,
    const float* __restrict__ b2, const float* __restrict__ ipb,
    const float* __restrict__ opb,
    _Float16* __restrict__ wsh, float* __restrict__ bu, float* __restrict__ b_eff)
{
    __shared__ __align__(16) float sbuf[8448];   // 33792 B
    int b = blockIdx.x, t = threadIdx.x;

    if (b < 2048) {
        // ---- zt: Z[c][x][y] f32 -> Zt[x][y][c] f16, y-tile 32 ----
        float (*sT)[33] = (float(*)[33])sbuf;
        int x = b >> 3, yt = (b & 7) * 32;
#pragma unroll
        for (int i = 0; i < 8; ++i) {
            int g = i * 256 + t;
            int c = g >> 3, y = (g & 7) * 4;
            float4 v = *(const float4*)(Z + (size_t)c * 65536 + x * 256 + yt + y);
            sT[c][y] = v.x; sT[c][y + 1] = v.y; sT[c][y + 2] = v.z; sT[c][y + 3] = v.w;
        }
        __syncthreads();
        _Float16* Zt = wsh + O_ZT;
        int c4 = (t & 63) * 4;
#pragma unroll
        for (int i = 0; i < 8; ++i) {
            int y = (t >> 6) * 8 + i;
            half4v o;
#pragma unroll
            for (int j = 0; j < 4; ++j) o[j] = (_Float16)sT[c4 + j][y];
            *(half4v*)(Zt + ((size_t)(x * 256 + yt + y)) * 256 + c4) = o;
        }
    } else if (b < 2240) {
        // ---- tw: weight transposes via LDS tiles ----
        float (*sT)[65] = (float(*)[65])sbuf;
        int bx = b - 2048;
        int sec = bx >> 6, tile = bx & 63;
        int th = tile >> 3, tl = tile & 7;
        int row0, col0;
        if (sec == 0) { row0 = tl * 64;             col0 = th * 64; }
        else          { row0 = 512 * sec + th * 64; col0 = tl * 64; }
        const float* src = ipw + (size_t)row0 * 512 + col0;
#pragma unroll
        for (int i = 0; i < 4; ++i) {
            int rr = i * 16 + (t >> 4), cc = (t & 15) * 4;
            float4 v = *(const float4*)(src + (size_t)rr * 512 + cc);
            sT[rr][cc] = v.x; sT[rr][cc + 1] = v.y; sT[rr][cc + 2] = v.z; sT[rr][cc + 3] = v.w;
        }
        __syncthreads();
        float scale = (sec == 1) ? 0.125f : 1.0f;
#pragma unroll
        for (int it = 0; it < 2; ++it) {
            int g = t + it * 256;
            int a = g >> 3, b8 = (g & 7) * 8;
            half8 o;
#pragma unroll
            for (int j = 0; j < 8; ++j) o[j] = (_Float16)(scale * sT[b8 + j][a]);
            size_t dst;
            if (sec == 0)      dst = O_WQT + (size_t)(th * 64 + a) * 512 + tl * 64 + b8;
            else if (sec == 1) dst = O_WKT + (size_t)th * 32768 + (size_t)(tl * 64 + a) * 64 + b8;
            else               dst = O_WVT + (size_t)th * 32768 + (size_t)(tl * 64 + a) * 64 + b8;
            *(half8*)(wsh + dst) = o;
        }
    } else if (b < 3264) {
        // ---- query build, 4 elems/thread ----
        int e4 = ((b - 2240) * 256 + t) * 4;
        int q = e4 >> 9, j = e4 & 511;
        half4v o;
        if (j < 256) {
            float4 v = *(const float4*)(q_z + q * 256 + j);
            o[0] = (_Float16)v.x; o[1] = (_Float16)v.y;
            o[2] = (_Float16)v.z; o[3] = (_Float16)v.w;
        } else {
            float q0 = Qm[q * 3], q1 = Qm[q * 3 + 1], q2 = Qm[q * 3 + 2];
#pragma unroll
            for (int u = 0; u < 4; ++u) {
                int m = j - 256 + u;
                o[u] = (_Float16)(q0 * w2[m * 3] + q1 * w2[m * 3 + 1] + q2 * w2[m * 3 + 2] + b2[m]);
            }
        }
        *(half4v*)(wsh + O_QRY + e4) = o;
    } else if (b < 3520) {
        // ---- wo copy, 4 elems/thread ----
        int e4 = ((b - 3264) * 256 + t) * 4;
        float4 v = *(const float4*)(opw + e4);
        half4v o;
        o[0] = (_Float16)v.x; o[1] = (_Float16)v.y; o[2] = (_Float16)v.z; o[3] = (_Float16)v.w;
        *(half4v*)(wsh + O_WO + e4) = o;
    } else if (b < 3536) {
        // ---- bu[c] = 0.125 * sum_d bq[h*64+d]*Wk[h*64+d][j]  (coalesced over c) ----
        int c = (b - 3520) * 256 + t;
        int h = c >> 9, j = c & 511;
        float s = 0.f;
#pragma unroll 4
        for (int d = 0; d < 64; ++d)
            s += ipb[512 + (h << 6) + d] * ipw[(size_t)(512 + (h << 6) + d) * 512 + j];
        bu[c] = 0.125f * s;
    } else {
        // ---- b_eff: one wave per output e, coalesced lane reads + shuffle reduce ----
        int e = (b - 3536) * 4 + (t >> 6), l = t & 63;
        const float* worow = opw + (size_t)e * 512;
        float s = 0.f;
#pragma unroll
        for (int i = 0; i < 8; ++i)
            s += ipb[1024 + l + 64 * i] * worow[l + 64 * i];
#pragma unroll
        for (int mm = 1; mm < 64; mm <<= 1) s += __shfl_xor(s, mm, 64);
        if (l == 0) b_eff[e] = s + opb[e];
    }
}

// ---- k_small2: two 64xK64 @ (512x64)^T weight GEMMs in one launch ----
// bx<64: WcT[(h*512+col)*512 + row] = (wqT @ wkT)^T ; bx>=64: Mt[row][4096] = wo @ wvT
__global__ __launch_bounds__(256) void k_small2(_Float16* __restrict__ wsh)
{
    __shared__ __align__(16) _Float16 sA[64][72];
    int bx = blockIdx.x;
    int job = bx >> 6, g6 = bx & 63;
    int rb = g6 & 7, h = g6 >> 3;
    int t = threadIdx.x, w = t >> 6, l = t & 63;
    const _Float16* A0 = wsh + (job ? O_WO : O_WQT) + (size_t)rb * 64 * 512 + h * 64;
    const _Float16* B0 = wsh + (job ? O_WVT : O_WKT) + (size_t)h * 512 * 64;
#pragma unroll
    for (int i = 0; i < 2; ++i) {
        int g = t + i * 256;
        int row = g >> 3, colg = (g & 7) * 8;
        *(half8*)&sA[row][colg] = *(const half8*)(A0 + (size_t)row * 512 + colg);
    }
    __syncthreads();
    f32x4 acc[4][8] = {};
    int arow = l & 15, kg = (l >> 4) << 3;
#pragma unroll
    for (int kk = 0; kk < 64; kk += 32) {
        half8 a[4], bb[8];
#pragma unroll
        for (int mt = 0; mt < 4; ++mt) a[mt] = *(const half8*)&sA[mt * 16 + arow][kk + kg];
#pragma unroll
        for (int nt = 0; nt < 8; ++nt) {
            int col = (w << 7) + nt * 16 + arow;
            bb[nt] = *(const half8*)(B0 + (size_t)col * 64 + kk + kg);
        }
#pragma unroll
        for (int mt = 0; mt < 4; ++mt)
#pragma unroll
            for (int nt = 0; nt < 8; ++nt)
                acc[mt][nt] = __builtin_amdgcn_mfma_f32_16x16x32_f16(a[mt], bb[nt], acc[mt][nt], 0, 0, 0);
    }
    if (job == 0) {
        _Float16* C = wsh + O_WCT;
#pragma unroll
        for (int mt = 0; mt < 4; ++mt)
#pragma unroll
            for (int nt = 0; nt < 8; ++nt) {
                int col = (h << 9) + (w << 7) + nt * 16 + arow;
                int row0 = rb * 64 + mt * 16 + ((l >> 4) << 2);
#pragma unroll
                for (int v = 0; v < 4; ++v)
                    C[(size_t)col * 512 + row0 + v] = (_Float16)acc[mt][nt][v];
            }
    } else {
        _Float16* C0 = wsh + O_MT + (size_t)rb * 64 * 4096 + h * 512;
#pragma unroll
        for (int mt = 0; mt < 4; ++mt)
#pragma unroll
            for (int nt = 0; nt < 8; ++nt)
#pragma unroll
                for (int v = 0; v < 4; ++v) {
                    int row = mt * 16 + ((l >> 4) << 2) + v;
                    int col = (w << 7) + nt * 16 + arow;
                    C0[(size_t)row * 4096 + col] = (_Float16)acc[mt][nt][v];
                }
    }
}

// ---- k_mid: gemmU (blocks [0,512), K-split LDS) + passA (blocks [512,4608)) ----
__global__ __launch_bounds__(256, 4) void k_mid(
    const float* __restrict__ r, _Float16* __restrict__ wsh,
    const float* __restrict__ bu)
{
    __shared__ __align__(16) unsigned char smem[33792];
    int b = blockIdx.x, t = threadIdx.x, w = t >> 6, l = t & 63;

    if (b < 512) {
        // ---- gemmU: U = query @ WcT^T + bu, 64x256 out tile, K split in 2 LDS stages ----
        _Float16 (*sA)[264] = (_Float16(*)[264])smem;
        const _Float16* A = wsh + O_QRY;
        const _Float16* B = wsh + O_WCT;
        _Float16* U = wsh + O_U;
        int q0 = (b & 31) * 64;
        int colb = (b >> 5) * 256 + w * 64;
        f32x4 acc[4][4] = {};
        int arow = l & 15, kg = (l >> 4) << 3;
#pragma unroll
        for (int half = 0; half < 2; ++half) {
#pragma unroll
            for (int i = 0; i < 8; ++i) {
                int e = i * 2048 + t * 8;
                *(half8*)&sA[e >> 8][e & 255] =
                    *(const half8*)(A + (size_t)(q0 + (e >> 8)) * 512 + half * 256 + (e & 255));
            }
            __syncthreads();
#pragma unroll 2
            for (int kk = 0; kk < 256; kk += 32) {
                half8 a[4], bb[4];
#pragma unroll
                for (int mt = 0; mt < 4; ++mt) a[mt] = *(const half8*)&sA[mt * 16 + arow][kk + kg];
#pragma unroll
                for (int nt = 0; nt < 4; ++nt)
                    bb[nt] = *(const half8*)(B + (size_t)(colb + nt * 16 + arow) * 512 + half * 256 + kk + kg);
#pragma unroll
                for (int mt = 0; mt < 4; ++mt)
#pragma unroll
                    for (int nt = 0; nt < 4; ++nt)
                        acc[mt][nt] = __builtin_amdgcn_mfma_f32_16x16x32_f16(a[mt], bb[nt], acc[mt][nt], 0, 0, 0);
            }
            __syncthreads();
        }
#pragma unroll
        for (int mt = 0; mt < 4; ++mt)
#pragma unroll
            for (int nt = 0; nt < 4; ++nt)
#pragma unroll
                for (int v = 0; v < 4; ++v) {
                    int row = q0 + mt * 16 + ((l >> 4) << 2) + v;
                    int col = colb + nt * 16 + arow;
                    U[(size_t)row * 4096 + col] = (_Float16)(acc[mt][nt][v] + bu[col]);
                }
    } else {
        // ---- passA: bilinear interp, channel-contiguous -> Zr[ch][qp][col] ----
        float (*sT)[33] = (float(*)[33])smem;
        const _Float16* Zt = wsh + O_ZT;
        _Float16* Zr = wsh + O_ZR;
        int pb = b - 512;
        const float2* r2 = (const float2*)r;
#pragma unroll 2
        for (int i = 0; i < 8; ++i) {
            int ptl = w * 8 + i;
            float2 rv = r2[pb * 32 + ptl];
            int x1 = (int)rv.x, y1 = (int)rv.y;
            float dx = rv.x - (float)x1, dy = rv.y - (float)y1;
            float w11 = (1.f - dx) * (1.f - dy), w21 = dx * (1.f - dy);
            float w12 = (1.f - dx) * dy,         w22 = dx * dy;
            const _Float16* base = Zt + ((size_t)(x1 * 256 + y1)) * 256;
#pragma unroll
            for (int cg = 0; cg < 2; ++cg) {
                int c = cg * 128 + l * 2;
                half2v z11 = *(const half2v*)(base + c);
                half2v z12 = *(const half2v*)(base + 256 + c);
                half2v z21 = *(const half2v*)(base + 65536 + c);
                half2v z22 = *(const half2v*)(base + 65536 + 256 + c);
                sT[c][ptl]     = w11 * (float)z11[0] + w21 * (float)z21[0]
                               + w12 * (float)z12[0] + w22 * (float)z22[0];
                sT[c + 1][ptl] = w11 * (float)z11[1] + w21 * (float)z21[1]
                               + w12 * (float)z12[1] + w22 * (float)z22[1];
            }
        }
        __syncthreads();
        int ch0 = t >> 2, colc = (t & 3) * 8;
#pragma unroll
        for (int g = 0; g < 4; ++g) {
            int ch = g * 64 + ch0;
            half8 o;
#pragma unroll
            for (int j = 0; j < 8; ++j) o[j] = (_Float16)sT[ch][colc + j];
            *(half8*)(Zr + (size_t)ch * 131072 + pb * 32 + colc) = o;
        }
    }
}

// ---------------- main: key tile -> MFMA scores (split-K, 8 waves) -> softmax -> MFMA g ----------------
__global__ __launch_bounds__(512, 2) void k_main(
    const _Float16* __restrict__ Zr, const float* __restrict__ r,
    const float* __restrict__ w1, const float* __restrict__ b1,
    const _Float16* __restrict__ U, _Float16* __restrict__ G)
{
    __shared__ __align__(16) _Float16 sKey[64][520];
    __shared__ __align__(16) _Float16 sU[8][520];     // u[q]; reused as sG after scores
    __shared__ float sP[512];
    __shared__ float sP2[512];
    __shared__ __align__(16) _Float16 sA16[16][72];   // attn in A-fragment layout

    int q = blockIdx.x;
    int t = threadIdx.x, w = t >> 6, l = t & 63;
    int ch = q >> 3, s8 = q & 7;

    // zero sA16 (rows 8-15 feed MFMA as zeros)
    for (int i = t; i < 576; i += 512) ((unsigned*)sA16)[i] = 0u;

    // Z-part of key: contiguous 32KB
    const _Float16* src = Zr + ((size_t)ch * 2048 + s8 * 256) * 64;
#pragma unroll
    for (int i = 0; i < 4; ++i) {
        int e = i * 4096 + t * 8;
        *(half8*)&sKey[e >> 8][e & 255] = *(const half8*)(src + e);
    }
    // u[q]
    {
        int e = t * 8;
        *(half8*)&sU[e >> 9][e & 511] = *(const half8*)(U + (size_t)q * 4096 + e);
    }
    // r_proj
    {
        int m = t & 255, half = t >> 8;
        float w10 = w1[2 * m], w11 = w1[2 * m + 1], b1m = b1[m];
        const float2* r2q = (const float2*)r + (size_t)q * 64;
#pragma unroll 8
        for (int i = 0; i < 32; ++i) {
            int k = half * 32 + i;
            float2 rv = r2q[k];
            sKey[k][256 + m] = (_Float16)(rv.x * w10 + rv.y * w11 + b1m);
        }
    }
    __syncthreads();

    // scores via MFMA, split-K: waves 0-3 do K[0,256) -> sP, waves 4-7 K[256,512) -> sP2
    {
        f32x4 acc = {};
        int arow = l & 15, kg = (l >> 4) << 3;
        int wm = w & 3, khalf = (w >> 2) << 8;
        const _Float16* ar = &sKey[wm * 16 + arow][khalf + kg];
        const _Float16* br = &sU[l & 7][khalf + kg];
#pragma unroll
        for (int kk = 0; kk < 256; kk += 32)
            acc = __builtin_amdgcn_mfma_f32_16x16x32_f16(
                *(const half8*)(ar + kk), *(const half8*)(br + kk), acc, 0, 0, 0);
        if ((l & 15) < 8) {
            int h = l & 15, krow0 = wm * 16 + ((l >> 4) << 2);
            float* dst = (w < 4) ? sP : sP2;
#pragma unroll
            for (int v = 0; v < 4; ++v) dst[(h << 6) + krow0 + v] = acc[v];
        }
    }
    __syncthreads();

    // softmax per head (wave == head); store attn f16 in A-frag layout
    {
        float v = sP[t] + sP2[t];
        float mx = v;
#pragma unroll
        for (int mm = 1; mm < 64; mm <<= 1) mx = fmaxf(mx, __shfl_xor(mx, mm, 64));
        float e = __expf(v - mx);
        float sm = e;
#pragma unroll
        for (int mm = 1; mm < 64; mm <<= 1) sm += __shfl_xor(sm, mm, 64);
        sA16[w][l] = (_Float16)(e / sm);
    }
    __syncthreads();

    // g = attn @ key via MFMA; wave w covers cols [w*64, w*64+64)
    {
        f32x4 acc[4] = {};
        int arow = l & 15, kq = (l >> 4) << 3;
        half8 a0 = *(const half8*)&sA16[arow][kq];
        half8 a1 = *(const half8*)&sA16[arow][32 + kq];
#pragma unroll
        for (int nt = 0; nt < 4; ++nt) {
            int n0 = (w << 6) + (nt << 4);
            half8 b0, b1f;
#pragma unroll
            for (int jj = 0; jj < 8; ++jj) b0[jj] = sKey[kq + jj][n0 + arow];
            acc[nt] = __builtin_amdgcn_mfma_f32_16x16x32_f16(a0, b0, acc[nt], 0, 0, 0);
#pragma unroll
            for (int jj = 0; jj < 8; ++jj) b1f[jj] = sKey[32 + kq + jj][n0 + arow];
            acc[nt] = __builtin_amdgcn_mfma_f32_16x16x32_f16(a1, b1f, acc[nt], 0, 0, 0);
        }
        if (l < 32) {
            int rgrp = (l >> 4) << 2;
#pragma unroll
            for (int nt = 0; nt < 4; ++nt) {
                int n0 = (w << 6) + (nt << 4);
#pragma unroll
                for (int v = 0; v < 4; ++v)
                    sU[rgrp + v][n0 + arow] = (_Float16)acc[nt][v];
            }
        }
    }
    __syncthreads();

    // coalesced G write from sG(=sU)
    {
        int c = t * 8;
        *(half8*)(G + (size_t)q * 4096 + c) = *(const half8*)&sU[c >> 9][c & 511];
    }
}

// ---------------- final: 64x128 tiles, grid (32,4) ----------------
__global__ __launch_bounds__(256) void k_final(
    const _Float16* __restrict__ G, const _Float16* __restrict__ Mt,
    const float* __restrict__ b_eff, const float* __restrict__ qz,
    float* __restrict__ out)
{
    __shared__ __align__(16) _Float16 sA[64][520];
    int rb = blockIdx.x, cb = blockIdx.y;
    int q0 = rb * 64;
    int t = threadIdx.x, w = t >> 6, l = t & 63;

    if (cb == 0) {
#pragma unroll
        for (int i = 0; i < 16; ++i) {
            int idx4 = i * 256 + t;
            int row = idx4 >> 6, c = (idx4 & 63) << 2;
            *(float4*)&out[(size_t)(q0 + row) * 768 + c] =
                *(const float4*)&qz[(size_t)(q0 + row) * 256 + c];
        }
    }

    f32x4 acc[4][2] = {};
    int arow = l & 15, kg = (l >> 4) << 3;
    int e0 = cb * 128 + (w << 5);
    for (int c = 0; c < 8; ++c) {
#pragma unroll
        for (int i = 0; i < 16; ++i) {
            int e = i * 2048 + t * 8;
            *(half8*)&sA[e >> 9][e & 511] =
                *(const half8*)(G + (size_t)(q0 + (e >> 9)) * 4096 + c * 512 + (e & 511));
        }
        __syncthreads();
#pragma unroll 4
        for (int kk = 0; kk < 512; kk += 32) {
            half8 a[4], bb[2];
#pragma unroll
            for (int nt = 0; nt < 2; ++nt)
                bb[nt] = *(const half8*)(Mt + (size_t)(e0 + nt * 16 + arow) * 4096 + c * 512 + kk + kg);
#pragma unroll
            for (int mt = 0; mt < 4; ++mt) {
                a[mt] = *(const half8*)&sA[mt * 16 + arow][kk + kg];
#pragma unroll
                for (int nt = 0; nt < 2; ++nt)
                    acc[mt][nt] = __builtin_amdgcn_mfma_f32_16x16x32_f16(a[mt], bb[nt], acc[mt][nt], 0, 0, 0);
            }
        }
        __syncthreads();
    }
#pragma unroll
    for (int mt = 0; mt < 4; ++mt)
#pragma unroll
        for (int nt = 0; nt < 2; ++nt)
#pragma unroll
            for (int v = 0; v < 4; ++v) {
                int row = q0 + mt * 16 + ((l >> 4) << 2) + v;
                int ecol = e0 + nt * 16 + arow;
                out[(size_t)row * 768 + 256 + ecol] = acc[mt][nt][v] + b_eff[ecol];
            }
}

extern "C" void kernel_launch(void* const* d_in, const int* in_sizes, int n_in,
                              void* d_out, int out_size, void* d_ws, size_t ws_size,
                              hipStream_t stream) {
    const float* Z          = (const float*)d_in[0];
    const float* Qm         = (const float*)d_in[1];
    const float* q_z        = (const float*)d_in[2];
    const float* r          = (const float*)d_in[3];
    const float* w1         = (const float*)d_in[4];
    const float* b1         = (const float*)d_in[5];
    const float* w2         = (const float*)d_in[6];
    const float* b2         = (const float*)d_in[7];
    const float* in_proj_w  = (const float*)d_in[8];
    const float* in_proj_b  = (const float*)d_in[9];
    const float* out_proj_w = (const float*)d_in[10];
    const float* out_proj_b = (const float*)d_in[11];
    float* out = (float*)d_out;

    _Float16* wsh = (_Float16*)d_ws;
    _Float16* Mt    = wsh + O_MT;
    _Float16* U     = wsh + O_U;
    _Float16* G     = wsh + O_G;
    _Float16* Zr    = wsh + O_ZR;
    float*    bu    = (float*)(wsh + O_F32);
    float*    b_eff = bu + 4096;

    k_pre<<<3664, 256, 0, stream>>>(Z, in_proj_w, out_proj_w, q_z, Qm, w2, b2,
                                    in_proj_b, out_proj_b, wsh, bu, b_eff);
    k_small2<<<128, 256, 0, stream>>>(wsh);
    k_mid<<<4608, 256, 0, stream>>>(r, wsh, bu);
    k_main<<<2048, 512, 0, stream>>>(Zr, r, w1, b1, U, G);
    k_final<<<dim3(32, 4), 256, 0, stream>>>(G, Mt, b_eff, q_z, out);
}